// Round 15
// baseline (450.536 us; speedup 1.0000x reference)
//
#include <hip/hip_runtime.h>
#include <hip/hip_bf16.h>

#define N_NODES 100000
#define E_EDGES 400000
#define NPAD 100096   // 1564 * 64

typedef unsigned short u16;
typedef __attribute__((ext_vector_type(4))) float f32x4;
typedef __attribute__((ext_vector_type(8))) short bf16x8;

__device__ inline u16 f2b(float v) {
    __hip_bfloat16 h = __float2bfloat16(v);
    return *reinterpret_cast<u16*>(&h);
}
__device__ inline float b2f(u16 u) { return __uint_as_float(((unsigned)u) << 16); }

__device__ inline void gld_lds16(const u16* g, u16* l) {
    __builtin_amdgcn_global_load_lds(
        (const __attribute__((address_space(1))) unsigned*)g,
        (__attribute__((address_space(3))) unsigned*)l, 16, 0, 0);
}

// ---------------- fold W2/b2 into Wcat: Wcat2p[512][256] bf16, bias2[512] f32 ----------
__global__ __launch_bounds__(128) void k_fold(
    const float* __restrict__ W2, const float* __restrict__ Wih,
    const float* __restrict__ Whh, const float* __restrict__ bih,
    const float* __restrict__ bhh, const float* __restrict__ b2,
    u16* __restrict__ Wcat2p, float* __restrict__ bias2) {
    int c = blockIdx.x, t = threadIdx.x;
    __shared__ float wrow[128];
    __shared__ float red[128];
    wrow[t] = (c < 384) ? Wih[c * 128 + t] : 0.f;
    __syncthreads();
    float a = 0.f;
    for (int m = 0; m < 128; ++m) a += W2[t * 128 + m] * wrow[m];
    Wcat2p[c * 256 + t] = f2b(a);
    float dv = (c < 256) ? Whh[c * 128 + t] : (c >= 384 ? Whh[(c - 128) * 128 + t] : 0.f);
    Wcat2p[c * 256 + 128 + t] = f2b(dv);
    red[t] = b2[t] * wrow[t];
    __syncthreads();
    for (int o = 64; o; o >>= 1) { if (t < o) red[t] += red[t + o]; __syncthreads(); }
    if (t == 0) {
        float b = (c < 256) ? bih[c] + bhh[c] + red[0]
                : (c < 384 ? bih[c] + red[0] : bhh[c - 128]);
        bias2[c] = b;
    }
}

// ---------------- pack W1 + proj weights (Wc-fold computed inline) ----------------
__global__ __launch_bounds__(256) void k_pack(
    const float* __restrict__ W1,
    const float* __restrict__ Wq, const float* __restrict__ Wk,
    const float* __restrict__ Wv, const float* __restrict__ Ws,
    const float* __restrict__ Wc,
    const float* __restrict__ bq, const float* __restrict__ bk,
    const float* __restrict__ bv, const float* __restrict__ bs,
    const float* __restrict__ bc,
    u16* __restrict__ W1p, u16* __restrict__ Wprojp, float* __restrict__ bproj) {
    int i = blockIdx.x * 256 + threadIdx.x;
    if (i < 49152) { int n = i / 384, k2 = i % 384; W1p[i] = f2b(W1[k2 * 128 + n]); return; }
    i -= 49152;
    if (i < 98304) {
        int n = i / 128, k2 = i % 128; float v;
        if (n < 256)      v = Wq[k2 * 256 + n];
        else if (n < 512) v = Wk[k2 * 256 + (n - 256)];
        else if (n < 640) {
            int t = n - 512, h = t >> 6, o = t & 63;
            float a = 0.f;
            for (int c = 0; c < 128; ++c) a += Wv[k2 * 256 + h * 128 + c] * Wc[(h * 128 + c) * 64 + o];
            v = a;
        } else if (n < 704) {
            int o = n - 640;
            float a = 0.f;
            for (int j = 0; j < 256; ++j) a += Ws[k2 * 256 + j] * Wc[j * 64 + o];
            v = a;
        } else v = 0.f;
        Wprojp[i] = f2b(v); return;
    }
    i -= 98304;
    if (i < 768) {
        float v;
        if (i < 256)      v = bq[i];
        else if (i < 512) v = bk[i - 256];
        else if (i < 640) {
            int t = i - 512, h = t >> 6, o = t & 63;
            float a = 0.f;
            for (int c = 0; c < 128; ++c) a += bv[h * 128 + c] * Wc[(h * 128 + c) * 64 + o];
            v = a;
        } else if (i < 704) {
            int o = i - 640;
            float a = bc[o];
            for (int j = 0; j < 256; ++j) a += bs[j] * Wc[j * 64 + o];
            v = a;
        } else v = 0.f;
        bproj[i] = v;
    }
}

// ---------------- init ----------------
__global__ void k_init(int* __restrict__ winner, int* __restrict__ deg,
                       int* __restrict__ counters) {
    int n = blockIdx.x * 256 + threadIdx.x;
    if (n == 0) { counters[0] = 0; counters[1] = 0; }  // wcount, etot
    if (n < N_NODES) { winner[n] = -1; deg[n] = 0; }
}

// ---------------- edge pass: winner (max edge idx) + degree histogram ----------------
__global__ void k_edges(const int* __restrict__ ei, int* __restrict__ winner,
                        int* __restrict__ deg) {
    int e = blockIdx.x * 256 + threadIdx.x;
    if (e < E_EDGES) {
        int dst = ei[E_EDGES + e];
        atomicMax(&winner[dst], e);
        atomicAdd(&deg[dst], 1);
    }
}

// -------- node pass: compact winners (node, edge, src triples) + CSR alloc --------
__global__ void k_nodes(const int* __restrict__ winner, const int* __restrict__ deg,
                        const int* __restrict__ ei,
                        int* __restrict__ wnode, int* __restrict__ wedge,
                        int* __restrict__ wsrc, int* __restrict__ counters,
                        int* __restrict__ startA, int* __restrict__ cursor) {
    int n = blockIdx.x * 256 + threadIdx.x;
    if (n >= N_NODES) return;
    int we = winner[n];
    if (we >= 0) {
        int i = atomicAdd(&counters[0], 1);
        wnode[i] = n;
        wedge[i] = we;
        wsrc[i] = ei[we];
    }
    int d = deg[n];
    int st = d ? atomicAdd(&counters[1], d) : 0;
    startA[n] = st;
    cursor[n] = st;
}

// ---------------- fill CSR: segment holds src node of each in-edge ----------------
__global__ void k_fill(const int* __restrict__ ei, int* __restrict__ cursor,
                       int* __restrict__ esrc) {
    int e = blockIdx.x * 256 + threadIdx.x;
    if (e < E_EDGES) {
        int dst = ei[E_EDGES + e];
        int pos = atomicAdd(&cursor[dst], 1);
        esrc[pos] = ei[e];
    }
}

// ---------------- x init (bf16 copy of memory; winner rows overwritten by k_mg) -------
__global__ void k_xinit(const float* __restrict__ mem, const int* __restrict__ winner,
                        u16* __restrict__ x) {
    size_t idx = ((size_t)blockIdx.x * 256 + threadIdx.x) * 4;
    if (idx >= (size_t)N_NODES * 128) return;
    if (winner[idx >> 7] >= 0) return;   // GRU will write this row
    float4 v = *(const float4*)(mem + idx);
    ushort4 o;
    o.x = f2b(v.x); o.y = f2b(v.y); o.z = f2b(v.z); o.w = f2b(v.w);
    *(ushort4*)(x + idx) = o;
}

// ========== fused gather + message-MLP + GRU for winner rows -> xb ==========
// EXACT r13 structure at (256,1) — the only proven-correct no-spill point
// (r7/r8/r9/r10 spilled; r14's (256,2) MIscompiled: absmax 3e-2, rule #18
// hazard exposed by regalloc change). Hardened: sched_barrier(0) after every
// counted-waitcnt asm pins MFMA/ds ordering against future rescheduling.
__global__ __launch_bounds__(256, 1) void k_mg(
    const float* __restrict__ mem, const float* __restrict__ eattr,
    const int* __restrict__ wnode, const int* __restrict__ wedge,
    const int* __restrict__ wsrc, const int* __restrict__ Mp,
    const u16* __restrict__ W1p, const float* __restrict__ b1,
    const u16* __restrict__ Wcat2p, const float* __restrict__ bias2,
    u16* __restrict__ xb) {
    __shared__ u16 lB[3][128 * 64];   // 48 KB ring
    __shared__ u16 h1l[64][136];      // 17.4 KB, padded rows

    const int tid = threadIdx.x;
    const int wid = tid >> 6, lane = tid & 63;
    const int lrow = lane & 15, lhi = lane >> 4;
    const int M = *Mp;
    const int arow0 = blockIdx.x * 64;
    if (arow0 >= M) return;

    const int rowg = arow0 + wid * 16 + lrow;
    const int rowc = min(rowg, M - 1);
    const int node = wnode[rowc];
    const int we = wedge[rowc];
    const int src = wsrc[rowc];

    // gather A fragments FIRST (consumed by converts before staging loads matter)
    bf16x8 af[12];
#pragma unroll
    for (int ks = 0; ks < 12; ++ks) {
        int c = ks * 4 + lhi;
        const float* p;
        if (c < 16)      p = mem + (size_t)src * 128 + c * 8;
        else if (c < 32) p = mem + (size_t)node * 128 + (c - 16) * 8;
        else             p = eattr + (size_t)we * 128 + (c - 32) * 8;
        float4 v0 = *(const float4*)p;
        float4 v1 = *(const float4*)(p + 4);
        bf16x8 a;
        a[0] = (short)f2b(v0.x); a[1] = (short)f2b(v0.y);
        a[2] = (short)f2b(v0.z); a[3] = (short)f2b(v0.w);
        a[4] = (short)f2b(v1.x); a[5] = (short)f2b(v1.y);
        a[6] = (short)f2b(v1.z); a[7] = (short)f2b(v1.w);
        af[ks] = a;
    }

    // unified tile stream: t=0..5 -> W1p kt=t ; t=6..21 -> Wcat2p g=t-6
    auto stTile = [&](int t) {
        const u16* Bp; int K, rowoff, kt;
        if (t < 6) { Bp = W1p; K = 384; rowoff = 0; kt = t; }
        else { int g = t - 6; Bp = Wcat2p; K = 256; rowoff = (g >> 2) * 128; kt = g & 3; }
        u16* dst = (u16*)lB[t % 3];
#pragma unroll
        for (int i = 0; i < 4; ++i) {
            int chunk = i * 256 + wid * 64 + lane;
            int row = chunk >> 3, cc = chunk & 7;
            int ccs = cc ^ (row & 7);
            gld_lds16(Bp + (size_t)(rowoff + row) * K + kt * 64 + ccs * 8,
                      &dst[(i * 256 + wid * 64) * 8]);
        }
    };
    stTile(0); stTile(1);   // 8 loads/wave in flight (2 tiles)

    // ---- GEMM1: tiles 0..5, acc1 ----
    f32x4 acc1[8] = {};
#pragma unroll
    for (int t = 0; t < 6; ++t) {
        asm volatile("s_waitcnt vmcnt(4)\ns_barrier" ::: "memory");
        __builtin_amdgcn_sched_barrier(0);
        stTile(t + 2);
        const u16* lBc = lB[t % 3];
#pragma unroll
        for (int ks = 0; ks < 2; ++ks) {
            bf16x8 bf[8];
#pragma unroll
            for (int n2 = 0; n2 < 8; ++n2) {
                int chunk = (ks * 4 + lhi) ^ (lrow & 7);
                bf[n2] = *(const bf16x8*)&lBc[(size_t)(n2 * 16 + lrow) * 64 + chunk * 8];
            }
#pragma unroll
            for (int n2 = 0; n2 < 8; ++n2)
                acc1[n2] = __builtin_amdgcn_mfma_f32_16x16x32_bf16(
                    bf[n2], af[t * 2 + ks], acc1[n2], 0, 0, 0);
        }
    }

    // h1 -> LDS (intra-wave rows; visibility via lgkmcnt(0) at PASS A entry)
    {
        const int rl = wid * 16 + lrow;
#pragma unroll
        for (int n2 = 0; n2 < 8; ++n2) {
            int col = n2 * 16 + lhi * 4;
            float4 bv = *(const float4*)&b1[col];
            ushort4 o;
            o.x = f2b(fmaxf(acc1[n2][0] + bv.x, 0.f));
            o.y = f2b(fmaxf(acc1[n2][1] + bv.y, 0.f));
            o.z = f2b(fmaxf(acc1[n2][2] + bv.z, 0.f));
            o.w = f2b(fmaxf(acc1[n2][3] + bv.w, 0.f));
            *(ushort4*)&h1l[rl][col] = o;
        }
    }

    // ---- GEMM2 PASS A: global tiles 6..13 (quads 0,1 = R,Z) ----
    f32x4 accP[8] = {}, accQ[8] = {};
    bf16x8 af2[4];
#pragma unroll
    for (int tt = 0; tt < 8; ++tt) {
        if (tt == 0) {
            asm volatile("s_waitcnt vmcnt(4) lgkmcnt(0)\ns_barrier" ::: "memory");
            __builtin_amdgcn_sched_barrier(0);
        } else {
            asm volatile("s_waitcnt vmcnt(4)\ns_barrier" ::: "memory");
            __builtin_amdgcn_sched_barrier(0);
        }
        stTile(8 + tt);
        if (tt == 0) {
#pragma unroll
            for (int ks = 0; ks < 4; ++ks)
                af2[ks] = *(const bf16x8*)&h1l[wid * 16 + lrow][ks * 32 + lhi * 8];
        }
        const u16* lBc = lB[(6 + tt) % 3];
#pragma unroll
        for (int ks = 0; ks < 2; ++ks) {
            const int kk = (tt & 3) * 2 + ks;
            bf16x8 a = (kk < 4) ? af2[kk] : af[kk];
            bf16x8 bf[8];
#pragma unroll
            for (int n2 = 0; n2 < 8; ++n2) {
                int chunk = (ks * 4 + lhi) ^ (lrow & 7);
                bf[n2] = *(const bf16x8*)&lBc[(size_t)(n2 * 16 + lrow) * 64 + chunk * 8];
            }
            if (tt < 4) {
#pragma unroll
                for (int n2 = 0; n2 < 8; ++n2)
                    accP[n2] = __builtin_amdgcn_mfma_f32_16x16x32_bf16(
                        bf[n2], a, accP[n2], 0, 0, 0);
            } else {
#pragma unroll
                for (int n2 = 0; n2 < 8; ++n2)
                    accQ[n2] = __builtin_amdgcn_mfma_f32_16x16x32_bf16(
                        bf[n2], a, accQ[n2], 0, 0, 0);
            }
        }
    }

    // ---- between passes: r = sigmoid(R), z = sigmoid(Z) -> packed bf16 pairs ----
    unsigned rz[32];
#pragma unroll
    for (int n2 = 0; n2 < 8; ++n2) {
        int col = n2 * 16 + lhi * 4;
        float4 br = *(const float4*)&bias2[col];
        float4 bz = *(const float4*)&bias2[128 + col];
#pragma unroll
        for (int j = 0; j < 4; ++j) {
            float bR = (j == 0) ? br.x : (j == 1) ? br.y : (j == 2) ? br.z : br.w;
            float bZ = (j == 0) ? bz.x : (j == 1) ? bz.y : (j == 2) ? bz.z : bz.w;
            float r = 1.f / (1.f + expf(-(accP[n2][j] + bR)));
            float z = 1.f / (1.f + expf(-(accQ[n2][j] + bZ)));
            rz[n2 * 4 + j] = (unsigned)f2b(r) | ((unsigned)f2b(z) << 16);
        }
        accP[n2] = (f32x4){0.f, 0.f, 0.f, 0.f};
        accQ[n2] = (f32x4){0.f, 0.f, 0.f, 0.f};
    }

    // ---- GEMM2 PASS B: global tiles 14..21 (quads 2,3 = IN,HN) ----
#pragma unroll
    for (int tt = 0; tt < 8; ++tt) {
        if (tt <= 6) {
            asm volatile("s_waitcnt vmcnt(4)\ns_barrier" ::: "memory");
            __builtin_amdgcn_sched_barrier(0);
        } else {
            asm volatile("s_waitcnt vmcnt(0)\ns_barrier" ::: "memory");
            __builtin_amdgcn_sched_barrier(0);
        }
        if (tt <= 5) stTile(16 + tt);
        const u16* lBc = lB[(14 + tt) % 3];
#pragma unroll
        for (int ks = 0; ks < 2; ++ks) {
            const int kk = (tt & 3) * 2 + ks;
            bf16x8 a = (kk < 4) ? af2[kk] : af[kk];
            bf16x8 bf[8];
#pragma unroll
            for (int n2 = 0; n2 < 8; ++n2) {
                int chunk = (ks * 4 + lhi) ^ (lrow & 7);
                bf[n2] = *(const bf16x8*)&lBc[(size_t)(n2 * 16 + lrow) * 64 + chunk * 8];
            }
            if (tt < 4) {
#pragma unroll
                for (int n2 = 0; n2 < 8; ++n2)
                    accP[n2] = __builtin_amdgcn_mfma_f32_16x16x32_bf16(
                        bf[n2], a, accP[n2], 0, 0, 0);
            } else {
#pragma unroll
                for (int n2 = 0; n2 < 8; ++n2)
                    accQ[n2] = __builtin_amdgcn_mfma_f32_16x16x32_bf16(
                        bf[n2], a, accQ[n2], 0, 0, 0);
            }
        }
    }

    // ---- GRU epilogue -> xb[node] (accP=IN, accQ=HN) ----
    if (rowg >= M) return;
#pragma unroll
    for (int n2 = 0; n2 < 8; ++n2) {
        int col = n2 * 16 + lhi * 4;
        float4 bn = *(const float4*)&bias2[256 + col];
        float4 bh = *(const float4*)&bias2[384 + col];
        float4 hv = *(const float4*)&mem[(size_t)node * 128 + col];
        ushort4 o;
#pragma unroll
        for (int j = 0; j < 4; ++j) {
            float bN = (j == 0) ? bn.x : (j == 1) ? bn.y : (j == 2) ? bn.z : bn.w;
            float bH = (j == 0) ? bh.x : (j == 1) ? bh.y : (j == 2) ? bh.z : bh.w;
            float hj = (j == 0) ? hv.x : (j == 1) ? hv.y : (j == 2) ? hv.z : hv.w;
            unsigned p = rz[n2 * 4 + j];
            float r = b2f((u16)(p & 0xffff));
            float z = b2f((u16)(p >> 16));
            float n = tanhf(accP[n2][j] + bN + r * (accQ[n2][j] + bH));
            u16 res = f2b((1.f - z) * n + z * hj);
            if (j == 0) o.x = res; else if (j == 1) o.y = res;
            else if (j == 2) o.z = res; else o.w = res;
        }
        *(ushort4*)&xb[(size_t)node * 128 + col] = o;
    }
}

// ================= proj GEMM: r12 pipeline, 3-buffer ring (LDS 64KB) =========
template <int K, int NQUAD>
__global__ __launch_bounds__(256, 1) void k_proj(
    const u16* __restrict__ A, const u16* __restrict__ Bp,
    const float* __restrict__ bias, int Mmax,
    u16* __restrict__ qb, u16* __restrict__ kb, u16* __restrict__ vcb,
    float* __restrict__ outf) {
    constexpr int KT = K / 64;          // 2
    constexpr int NT = NQUAD * KT;      // 12
    constexpr int NKS = K / 32;         // 4
    constexpr int CPR = K / 8;          // 16
    __shared__ u16 lA[64 * K];          // 16 KB
    __shared__ u16 lB[3][128 * 64];     // 48 KB ring

    const int tid = threadIdx.x;
    const int wid = tid >> 6, lane = tid & 63;
    const int lrow = lane & 15, lhi = lane >> 4;
    const int arow0 = blockIdx.x * 64;

#pragma unroll
    for (int i = 0; i < (64 * CPR) / 256; ++i) {
        int chunk = i * 256 + wid * 64 + lane;
        int row = chunk / CPR, cc = chunk % CPR;
        int ccs = (cc & ~7) | ((cc ^ row) & 7);
        gld_lds16(A + (size_t)(arow0 + row) * K + ccs * 8, &lA[(i * 256 + wid * 64) * 8]);
    }
    auto stTile = [&](int t) {
        int q = t / KT, kt = t - q * KT;
        u16* dst = (u16*)lB[t % 3];
#pragma unroll
        for (int i = 0; i < 4; ++i) {
            int chunk = i * 256 + wid * 64 + lane;
            int row = chunk >> 3, cc = chunk & 7;
            int ccs = cc ^ (row & 7);
            gld_lds16(Bp + (size_t)(q * 128 + row) * K + kt * 64 + ccs * 8,
                      &dst[(i * 256 + wid * 64) * 8]);
        }
    };
    stTile(0); stTile(1);
    // wait lA (oldest 4 of 12 outstanding) + barrier; 8 tile loads stay in flight
    asm volatile("s_waitcnt vmcnt(8)\ns_barrier" ::: "memory");
    __builtin_amdgcn_sched_barrier(0);

    bf16x8 af[NKS];
#pragma unroll
    for (int ks = 0; ks < NKS; ++ks) {
        int chunk = ks * 4 + lhi;
        int ccs = (chunk & ~7) | ((chunk ^ lrow) & 7);
        af[ks] = *(const bf16x8*)&lA[(size_t)(wid * 16 + lrow) * K + ccs * 8];
    }

    f32x4 acc[NQUAD][8] = {};
#pragma unroll
    for (int t = 0; t < NT; ++t) {
        if (t <= NT - 2) {
            asm volatile("s_waitcnt vmcnt(4)\ns_barrier" ::: "memory");
            __builtin_amdgcn_sched_barrier(0);
        } else {
            asm volatile("s_waitcnt vmcnt(0)\ns_barrier" ::: "memory");
            __builtin_amdgcn_sched_barrier(0);
        }
        if (t + 2 < NT) stTile(t + 2);
        const int q = t / KT, kt = t - q * KT;
        const u16* lBc = lB[t % 3];
#pragma unroll
        for (int ks = 0; ks < 2; ++ks) {
            bf16x8 bf[8];
#pragma unroll
            for (int n2 = 0; n2 < 8; ++n2) {
                int chunk = (ks * 4 + lhi) ^ (lrow & 7);
                bf[n2] = *(const bf16x8*)&lBc[(size_t)(n2 * 16 + lrow) * 64 + chunk * 8];
            }
#pragma unroll
            for (int n2 = 0; n2 < 8; ++n2)
                acc[q][n2] = __builtin_amdgcn_mfma_f32_16x16x32_bf16(
                    bf[n2], af[kt * 2 + ks], acc[q][n2], 0, 0, 0);
        }
    }

    const int rowg = arow0 + wid * 16 + lrow;
    if (rowg >= Mmax) return;

#pragma unroll
    for (int q = 0; q < NQUAD; ++q) {
#pragma unroll
        for (int n2 = 0; n2 < 8; ++n2) {
            int colg = q * 128 + n2 * 16 + lhi * 4;
            if (colg >= 704) continue;
            float4 bv = *(const float4*)&bias[colg];
            float v0 = acc[q][n2][0] + bv.x, v1 = acc[q][n2][1] + bv.y;
            float v2 = acc[q][n2][2] + bv.z, v3 = acc[q][n2][3] + bv.w;
            if (colg < 640) {
                ushort4 o;
                o.x = f2b(v0); o.y = f2b(v1); o.z = f2b(v2); o.w = f2b(v3);
                if (colg < 256)
                    *(ushort4*)&qb[(size_t)rowg * 256 + colg] = o;
                else if (colg < 512)
                    *(ushort4*)&kb[(size_t)rowg * 256 + (colg - 256)] = o;
                else
                    *(ushort4*)&vcb[(size_t)rowg * 128 + (colg - 512)] = o;
            } else {
                float4 o; o.x = v0; o.y = v1; o.z = v2; o.w = v3;
                *(float4*)&outf[(size_t)rowg * 64 + (colg - 640)] = o;
            }
        }
    }
}

// ---------------- CSR attention: one wave per dst, no atomics ----------------
// esrc prefetched one iteration ahead: k/vc gathers of edge p overlap the
// (contiguous, cheap) index load of edge p+1 — shortens the dependent chain.
__global__ __launch_bounds__(256) void k_attn(
    const u16* __restrict__ qB, const u16* __restrict__ kB, const u16* __restrict__ vcB,
    const int* __restrict__ startA, const int* __restrict__ deg,
    const int* __restrict__ esrc, float* __restrict__ out) {
    int wid = threadIdx.x >> 6, lane = threadIdx.x & 63;
    int dst = blockIdx.x * 4 + wid;
    if (dst >= N_NODES) return;
    int d = deg[dst];
    if (d == 0) return;
    int st = startA[dst];

    ushort4 qv = *(const ushort4*)&qB[(size_t)dst * 256 + lane * 4];
    float q0 = b2f(qv.x), q1 = b2f(qv.y), q2 = b2f(qv.z), q3 = b2f(qv.w);
    const float inv = 0.08838834764831845f;  // 1/sqrt(128)

    float s0 = 0.f, s1 = 0.f, accA = 0.f, accB = 0.f;
    int src = esrc[st];
    for (int p = st; p < st + d; ++p) {
        int src_next = (p + 1 < st + d) ? esrc[p + 1] : 0;
        ushort4 kv = *(const ushort4*)&kB[(size_t)src * 256 + lane * 4];
        float v0 = b2f(vcB[(size_t)src * 128 + lane]);
        float v1 = b2f(vcB[(size_t)src * 128 + 64 + lane]);
        float pp = q0 * b2f(kv.x) + q1 * b2f(kv.y) + q2 * b2f(kv.z) + q3 * b2f(kv.w);
        pp += __shfl_xor(pp, 1);
        pp += __shfl_xor(pp, 2);
        pp += __shfl_xor(pp, 4);
        pp += __shfl_xor(pp, 8);
        pp += __shfl_xor(pp, 16);
        float e = expf(pp * inv);
        float eo = __shfl_xor(e, 32);
        float e0 = (lane < 32) ? e : eo;
        float e1 = (lane < 32) ? eo : e;
        s0 += e0; s1 += e1;
        accA += e0 * v0;
        accB += e1 * v1;
        src = src_next;
    }
    float* op = out + (size_t)dst * 64 + lane;
    *op += accA / s0 + accB / s1;
}

extern "C" void kernel_launch(void* const* d_in, const int* in_sizes, int n_in,
                              void* d_out, int out_size, void* d_ws, size_t ws_size,
                              hipStream_t stream) {
    const float* memory = (const float*)d_in[0];
    const float* W1 = (const float*)d_in[1];  const float* b1 = (const float*)d_in[2];
    const float* W2 = (const float*)d_in[3];  const float* b2 = (const float*)d_in[4];
    const float* Wih = (const float*)d_in[5]; const float* Whh = (const float*)d_in[6];
    const float* bih = (const float*)d_in[7]; const float* bhh = (const float*)d_in[8];
    const float* Wq = (const float*)d_in[9];  const float* bq = (const float*)d_in[10];
    const float* Wk = (const float*)d_in[11]; const float* bk = (const float*)d_in[12];
    const float* Wv = (const float*)d_in[13]; const float* bv = (const float*)d_in[14];
    const float* Ws = (const float*)d_in[15]; const float* bs = (const float*)d_in[16];
    const float* Wc = (const float*)d_in[17]; const float* bc = (const float*)d_in[18];
    const float* eattr = (const float*)d_in[19];
    const int* ei = (const int*)d_in[21];
    float* out = (float*)d_out;

    char* ws = (char*)d_ws;
    size_t off = 0;
    auto alloc = [&](size_t bytes) -> char* {
        char* p = ws + off;
        off = (off + bytes + 255) & ~(size_t)255;
        return p;
    };
    u16* xb = (u16*)alloc((size_t)NPAD * 128 * 2);
    u16* qb = (u16*)alloc((size_t)NPAD * 256 * 2);
    u16* kb = (u16*)alloc((size_t)NPAD * 256 * 2);
    u16* vcb = (u16*)alloc((size_t)NPAD * 128 * 2);
    int* winner = (int*)alloc((size_t)N_NODES * 4);
    int* wnode = (int*)alloc((size_t)N_NODES * 4);
    int* wedge = (int*)alloc((size_t)N_NODES * 4);
    int* wsrc = (int*)alloc((size_t)N_NODES * 4);
    int* deg = (int*)alloc((size_t)N_NODES * 4);
    int* startA = (int*)alloc((size_t)N_NODES * 4);
    int* cursor = (int*)alloc((size_t)N_NODES * 4);
    int* esrc = (int*)alloc((size_t)E_EDGES * 4);
    int* counters = (int*)alloc(256);
    u16* W1p = (u16*)alloc(49152 * 2);
    u16* Wcat2p = (u16*)alloc(131072 * 2);
    u16* Wprojp = (u16*)alloc(98304 * 2);
    float* bias2 = (float*)alloc(512 * 4);
    float* bproj = (float*)alloc(768 * 4);
    (void)ws_size; (void)in_sizes; (void)n_in; (void)out_size;

    int* wcount = counters;  // counters[0]=wcount, counters[1]=etot

    hipLaunchKernelGGL(k_init, dim3(391), dim3(256), 0, stream, winner, deg, counters);
    hipLaunchKernelGGL(k_edges, dim3(1563), dim3(256), 0, stream, ei, winner, deg);
    hipLaunchKernelGGL(k_nodes, dim3(391), dim3(256), 0, stream,
                       winner, deg, ei, wnode, wedge, wsrc, counters, startA, cursor);
    hipLaunchKernelGGL(k_fill, dim3(1563), dim3(256), 0, stream, ei, cursor, esrc);
    hipLaunchKernelGGL(k_pack, dim3(579), dim3(256), 0, stream,
                       W1, Wq, Wk, Wv, Ws, Wc, bq, bk, bv, bs, bc, W1p, Wprojp, bproj);
    hipLaunchKernelGGL(k_fold, dim3(512), dim3(128), 0, stream,
                       W2, Wih, Whh, bih, bhh, b2, Wcat2p, bias2);
    hipLaunchKernelGGL(k_xinit, dim3(12500), dim3(256), 0, stream, memory, winner, xb);
    // fused gather + MLP + GRU for winner rows
    hipLaunchKernelGGL(k_mg, dim3(1564), dim3(256), 0, stream,
                       memory, eattr, wnode, wedge, wsrc, wcount,
                       W1p, b1, Wcat2p, bias2, xb);
    // proj: [q|k|vc|skip] = xb @ Wproj + bproj  (skip -> out, f32)
    hipLaunchKernelGGL((k_proj<128, 6>), dim3(1564), dim3(256), 0, stream,
                       xb, Wprojp, bproj, N_NODES, qb, kb, vcb, out);
    // CSR attention: out[dst] += sum(alpha * vc[src]) per head, no atomics
    hipLaunchKernelGGL(k_attn, dim3(25000), dim3(256), 0, stream,
                       qb, kb, vcb, startA, deg, esrc, out);
}

// Round 16
// 387.222 us; speedup vs baseline: 1.1635x; 1.1635x over previous
//
#include <hip/hip_runtime.h>
#include <hip/hip_bf16.h>

#define N_NODES 100000
#define E_EDGES 400000
#define NPAD 100096   // 782 * 128

typedef unsigned short u16;
typedef __attribute__((ext_vector_type(4))) float f32x4;
typedef __attribute__((ext_vector_type(8))) short bf16x8;

__device__ inline u16 f2b(float v) {
    __hip_bfloat16 h = __float2bfloat16(v);
    return *reinterpret_cast<u16*>(&h);
}
__device__ inline float b2f(u16 u) { return __uint_as_float(((unsigned)u) << 16); }

__device__ inline void gld_lds16(const u16* g, u16* l) {
    __builtin_amdgcn_global_load_lds(
        (const __attribute__((address_space(1))) unsigned*)g,
        (__attribute__((address_space(3))) unsigned*)l, 16, 0, 0);
}

// ---------------- fold W2/b2 into Wcat: Wcat2p[512][256] bf16, bias2[512] f32 ----------
__global__ __launch_bounds__(128) void k_fold(
    const float* __restrict__ W2, const float* __restrict__ Wih,
    const float* __restrict__ Whh, const float* __restrict__ bih,
    const float* __restrict__ bhh, const float* __restrict__ b2,
    u16* __restrict__ Wcat2p, float* __restrict__ bias2) {
    int c = blockIdx.x, t = threadIdx.x;
    __shared__ float wrow[128];
    __shared__ float red[128];
    wrow[t] = (c < 384) ? Wih[c * 128 + t] : 0.f;
    __syncthreads();
    float a = 0.f;
    for (int m = 0; m < 128; ++m) a += W2[t * 128 + m] * wrow[m];
    Wcat2p[c * 256 + t] = f2b(a);
    float dv = (c < 256) ? Whh[c * 128 + t] : (c >= 384 ? Whh[(c - 128) * 128 + t] : 0.f);
    Wcat2p[c * 256 + 128 + t] = f2b(dv);
    red[t] = b2[t] * wrow[t];
    __syncthreads();
    for (int o = 64; o; o >>= 1) { if (t < o) red[t] += red[t + o]; __syncthreads(); }
    if (t == 0) {
        float b = (c < 256) ? bih[c] + bhh[c] + red[0]
                : (c < 384 ? bih[c] + red[0] : bhh[c - 128]);
        bias2[c] = b;
    }
}

// ---------------- pack W1 + proj weights (Wc-fold computed inline) ----------------
__global__ __launch_bounds__(256) void k_pack(
    const float* __restrict__ W1,
    const float* __restrict__ Wq, const float* __restrict__ Wk,
    const float* __restrict__ Wv, const float* __restrict__ Ws,
    const float* __restrict__ Wc,
    const float* __restrict__ bq, const float* __restrict__ bk,
    const float* __restrict__ bv, const float* __restrict__ bs,
    const float* __restrict__ bc,
    u16* __restrict__ W1p, u16* __restrict__ Wprojp, float* __restrict__ bproj) {
    int i = blockIdx.x * 256 + threadIdx.x;
    if (i < 49152) { int n = i / 384, k2 = i % 384; W1p[i] = f2b(W1[k2 * 128 + n]); return; }
    i -= 49152;
    if (i < 98304) {
        int n = i / 128, k2 = i % 128; float v;
        if (n < 256)      v = Wq[k2 * 256 + n];
        else if (n < 512) v = Wk[k2 * 256 + (n - 256)];
        else if (n < 640) {
            int t = n - 512, h = t >> 6, o = t & 63;
            float a = 0.f;
            for (int c = 0; c < 128; ++c) a += Wv[k2 * 256 + h * 128 + c] * Wc[(h * 128 + c) * 64 + o];
            v = a;
        } else if (n < 704) {
            int o = n - 640;
            float a = 0.f;
            for (int j = 0; j < 256; ++j) a += Ws[k2 * 256 + j] * Wc[j * 64 + o];
            v = a;
        } else v = 0.f;
        Wprojp[i] = f2b(v); return;
    }
    i -= 98304;
    if (i < 768) {
        float v;
        if (i < 256)      v = bq[i];
        else if (i < 512) v = bk[i - 256];
        else if (i < 640) {
            int t = i - 512, h = t >> 6, o = t & 63;
            float a = 0.f;
            for (int c = 0; c < 128; ++c) a += bv[h * 128 + c] * Wc[(h * 128 + c) * 64 + o];
            v = a;
        } else if (i < 704) {
            int o = i - 640;
            float a = bc[o];
            for (int j = 0; j < 256; ++j) a += bs[j] * Wc[j * 64 + o];
            v = a;
        } else v = 0.f;
        bproj[i] = v;
    }
}

// ---------------- init ----------------
__global__ void k_init(int* __restrict__ winner, int* __restrict__ deg,
                       int* __restrict__ counters) {
    int n = blockIdx.x * 256 + threadIdx.x;
    if (n == 0) { counters[0] = 0; counters[1] = 0; }  // wcount, etot
    if (n < N_NODES) { winner[n] = -1; deg[n] = 0; }
}

// ---------------- edge pass: winner (max edge idx) + degree histogram ----------------
__global__ void k_edges(const int* __restrict__ ei, int* __restrict__ winner,
                        int* __restrict__ deg) {
    int e = blockIdx.x * 256 + threadIdx.x;
    if (e < E_EDGES) {
        int dst = ei[E_EDGES + e];
        atomicMax(&winner[dst], e);
        atomicAdd(&deg[dst], 1);
    }
}

// -------- node pass: compact winners (node, edge, src triples) + CSR alloc --------
__global__ void k_nodes(const int* __restrict__ winner, const int* __restrict__ deg,
                        const int* __restrict__ ei,
                        int* __restrict__ wnode, int* __restrict__ wedge,
                        int* __restrict__ wsrc, int* __restrict__ counters,
                        int* __restrict__ startA, int* __restrict__ cursor) {
    int n = blockIdx.x * 256 + threadIdx.x;
    if (n >= N_NODES) return;
    int we = winner[n];
    if (we >= 0) {
        int i = atomicAdd(&counters[0], 1);
        wnode[i] = n;
        wedge[i] = we;
        wsrc[i] = ei[we];
    }
    int d = deg[n];
    int st = d ? atomicAdd(&counters[1], d) : 0;
    startA[n] = st;
    cursor[n] = st;
}

// ---------------- fill CSR: segment holds src node of each in-edge ----------------
__global__ void k_fill(const int* __restrict__ ei, int* __restrict__ cursor,
                       int* __restrict__ esrc) {
    int e = blockIdx.x * 256 + threadIdx.x;
    if (e < E_EDGES) {
        int dst = ei[E_EDGES + e];
        int pos = atomicAdd(&cursor[dst], 1);
        esrc[pos] = ei[e];
    }
}

// ---------------- x init (bf16 copy of memory; winner rows overwritten by k_mg) -------
__global__ void k_xinit(const float* __restrict__ mem, const int* __restrict__ winner,
                        u16* __restrict__ x) {
    size_t idx = ((size_t)blockIdx.x * 256 + threadIdx.x) * 4;
    if (idx >= (size_t)N_NODES * 128) return;
    if (winner[idx >> 7] >= 0) return;   // GRU will write this row
    float4 v = *(const float4*)(mem + idx);
    ushort4 o;
    o.x = f2b(v.x); o.y = f2b(v.y); o.z = f2b(v.z); o.w = f2b(v.w);
    *(ushort4*)(x + idx) = o;
}

// ========== fused gather + message-MLP + GRU for winner rows -> xb ==========
// 512-thread block = 2 row-groups x 4 waves sharing the SAME B-tile stream:
// 8 waves/CU (2/SIMD) of latency hiding without a second block (every
// launch-bounds path failed r7-r10/r14). Per-wave staging halves (2 loads/
// tile -> vmcnt(2)). Register demand/wave unchanged (~232 <= 256 budget at
// 2 waves/SIMD). sched_barrier(0) after each counted-wait asm kept — fences
// the r14 hoisted-ds_read race. Canary: WRITE_SIZE ~24.5 MB.
__global__ __launch_bounds__(512, 1) void k_mg(
    const float* __restrict__ mem, const float* __restrict__ eattr,
    const int* __restrict__ wnode, const int* __restrict__ wedge,
    const int* __restrict__ wsrc, const int* __restrict__ Mp,
    const u16* __restrict__ W1p, const float* __restrict__ b1,
    const u16* __restrict__ Wcat2p, const float* __restrict__ bias2,
    u16* __restrict__ xb) {
    __shared__ u16 lB[3][128 * 64];     // 48 KB ring (shared by both groups)
    __shared__ u16 h1l[2][64][136];     // 34.8 KB, padded rows, per group

    const int tid = threadIdx.x;
    const int wid = tid >> 6, lane = tid & 63;
    const int grp = wid >> 2, wv = wid & 3;
    const int lrow = lane & 15, lhi = lane >> 4;
    const int M = *Mp;
    const int arow0 = blockIdx.x * 128;
    if (arow0 >= M) return;

    const int rowg = arow0 + grp * 64 + wv * 16 + lrow;
    const int rowc = min(rowg, M - 1);
    const int node = wnode[rowc];
    const int we = wedge[rowc];
    const int src = wsrc[rowc];

    // gather A fragments FIRST (consumed by converts before staging loads matter)
    bf16x8 af[12];
#pragma unroll
    for (int ks = 0; ks < 12; ++ks) {
        int c = ks * 4 + lhi;
        const float* p;
        if (c < 16)      p = mem + (size_t)src * 128 + c * 8;
        else if (c < 32) p = mem + (size_t)node * 128 + (c - 16) * 8;
        else             p = eattr + (size_t)we * 128 + (c - 32) * 8;
        float4 v0 = *(const float4*)p;
        float4 v1 = *(const float4*)(p + 4);
        bf16x8 a;
        a[0] = (short)f2b(v0.x); a[1] = (short)f2b(v0.y);
        a[2] = (short)f2b(v0.z); a[3] = (short)f2b(v0.w);
        a[4] = (short)f2b(v1.x); a[5] = (short)f2b(v1.y);
        a[6] = (short)f2b(v1.z); a[7] = (short)f2b(v1.w);
        af[ks] = a;
    }

    // unified tile stream: t=0..5 -> W1p kt=t ; t=6..21 -> Wcat2p g=t-6
    // 1024 16B-chunks per tile, 512 threads -> 2 gld_lds16 per thread.
    auto stTile = [&](int t) {
        const u16* Bp; int K, rowoff, kt;
        if (t < 6) { Bp = W1p; K = 384; rowoff = 0; kt = t; }
        else { int g = t - 6; Bp = Wcat2p; K = 256; rowoff = (g >> 2) * 128; kt = g & 3; }
        u16* dst = (u16*)lB[t % 3];
#pragma unroll
        for (int i = 0; i < 2; ++i) {
            int chunk = i * 512 + wid * 64 + lane;
            int row = chunk >> 3, cc = chunk & 7;
            int ccs = cc ^ (row & 7);
            gld_lds16(Bp + (size_t)(rowoff + row) * K + kt * 64 + ccs * 8,
                      &dst[(i * 512 + wid * 64) * 8]);
        }
    };
    stTile(0); stTile(1);   // 4 loads/wave in flight (2 tiles)

    // ---- GEMM1: tiles 0..5, acc1 ----
    f32x4 acc1[8] = {};
#pragma unroll
    for (int t = 0; t < 6; ++t) {
        asm volatile("s_waitcnt vmcnt(2)\ns_barrier" ::: "memory");
        __builtin_amdgcn_sched_barrier(0);
        stTile(t + 2);
        const u16* lBc = lB[t % 3];
#pragma unroll
        for (int ks = 0; ks < 2; ++ks) {
            bf16x8 bf[8];
#pragma unroll
            for (int n2 = 0; n2 < 8; ++n2) {
                int chunk = (ks * 4 + lhi) ^ (lrow & 7);
                bf[n2] = *(const bf16x8*)&lBc[(size_t)(n2 * 16 + lrow) * 64 + chunk * 8];
            }
#pragma unroll
            for (int n2 = 0; n2 < 8; ++n2)
                acc1[n2] = __builtin_amdgcn_mfma_f32_16x16x32_bf16(
                    bf[n2], af[t * 2 + ks], acc1[n2], 0, 0, 0);
        }
    }

    // h1 -> LDS (per-group buffer; visibility via lgkmcnt(0) at PASS A entry)
    {
        const int rl = wv * 16 + lrow;
#pragma unroll
        for (int n2 = 0; n2 < 8; ++n2) {
            int col = n2 * 16 + lhi * 4;
            float4 bv = *(const float4*)&b1[col];
            ushort4 o;
            o.x = f2b(fmaxf(acc1[n2][0] + bv.x, 0.f));
            o.y = f2b(fmaxf(acc1[n2][1] + bv.y, 0.f));
            o.z = f2b(fmaxf(acc1[n2][2] + bv.z, 0.f));
            o.w = f2b(fmaxf(acc1[n2][3] + bv.w, 0.f));
            *(ushort4*)&h1l[grp][rl][col] = o;
        }
    }

    // ---- GEMM2 PASS A: global tiles 6..13 (quads 0,1 = R,Z) ----
    f32x4 accP[8] = {}, accQ[8] = {};
    bf16x8 af2[4];
#pragma unroll
    for (int tt = 0; tt < 8; ++tt) {
        if (tt == 0) {
            asm volatile("s_waitcnt vmcnt(2) lgkmcnt(0)\ns_barrier" ::: "memory");
            __builtin_amdgcn_sched_barrier(0);
        } else {
            asm volatile("s_waitcnt vmcnt(2)\ns_barrier" ::: "memory");
            __builtin_amdgcn_sched_barrier(0);
        }
        stTile(8 + tt);
        if (tt == 0) {
#pragma unroll
            for (int ks = 0; ks < 4; ++ks)
                af2[ks] = *(const bf16x8*)&h1l[grp][wv * 16 + lrow][ks * 32 + lhi * 8];
        }
        const u16* lBc = lB[(6 + tt) % 3];
#pragma unroll
        for (int ks = 0; ks < 2; ++ks) {
            const int kk = (tt & 3) * 2 + ks;
            bf16x8 a = (kk < 4) ? af2[kk] : af[kk];
            bf16x8 bf[8];
#pragma unroll
            for (int n2 = 0; n2 < 8; ++n2) {
                int chunk = (ks * 4 + lhi) ^ (lrow & 7);
                bf[n2] = *(const bf16x8*)&lBc[(size_t)(n2 * 16 + lrow) * 64 + chunk * 8];
            }
            if (tt < 4) {
#pragma unroll
                for (int n2 = 0; n2 < 8; ++n2)
                    accP[n2] = __builtin_amdgcn_mfma_f32_16x16x32_bf16(
                        bf[n2], a, accP[n2], 0, 0, 0);
            } else {
#pragma unroll
                for (int n2 = 0; n2 < 8; ++n2)
                    accQ[n2] = __builtin_amdgcn_mfma_f32_16x16x32_bf16(
                        bf[n2], a, accQ[n2], 0, 0, 0);
            }
        }
    }

    // ---- between passes: r = sigmoid(R), z = sigmoid(Z) -> packed bf16 pairs ----
    unsigned rz[32];
#pragma unroll
    for (int n2 = 0; n2 < 8; ++n2) {
        int col = n2 * 16 + lhi * 4;
        float4 br = *(const float4*)&bias2[col];
        float4 bz = *(const float4*)&bias2[128 + col];
#pragma unroll
        for (int j = 0; j < 4; ++j) {
            float bR = (j == 0) ? br.x : (j == 1) ? br.y : (j == 2) ? br.z : br.w;
            float bZ = (j == 0) ? bz.x : (j == 1) ? bz.y : (j == 2) ? bz.z : bz.w;
            float r = 1.f / (1.f + expf(-(accP[n2][j] + bR)));
            float z = 1.f / (1.f + expf(-(accQ[n2][j] + bZ)));
            rz[n2 * 4 + j] = (unsigned)f2b(r) | ((unsigned)f2b(z) << 16);
        }
        accP[n2] = (f32x4){0.f, 0.f, 0.f, 0.f};
        accQ[n2] = (f32x4){0.f, 0.f, 0.f, 0.f};
    }

    // ---- GEMM2 PASS B: global tiles 14..21 (quads 2,3 = IN,HN) ----
#pragma unroll
    for (int tt = 0; tt < 8; ++tt) {
        if (tt <= 6) {
            asm volatile("s_waitcnt vmcnt(2)\ns_barrier" ::: "memory");
            __builtin_amdgcn_sched_barrier(0);
        } else {
            asm volatile("s_waitcnt vmcnt(0)\ns_barrier" ::: "memory");
            __builtin_amdgcn_sched_barrier(0);
        }
        if (tt <= 5) stTile(16 + tt);
        const u16* lBc = lB[(14 + tt) % 3];
#pragma unroll
        for (int ks = 0; ks < 2; ++ks) {
            const int kk = (tt & 3) * 2 + ks;
            bf16x8 a = (kk < 4) ? af2[kk] : af[kk];
            bf16x8 bf[8];
#pragma unroll
            for (int n2 = 0; n2 < 8; ++n2) {
                int chunk = (ks * 4 + lhi) ^ (lrow & 7);
                bf[n2] = *(const bf16x8*)&lBc[(size_t)(n2 * 16 + lrow) * 64 + chunk * 8];
            }
            if (tt < 4) {
#pragma unroll
                for (int n2 = 0; n2 < 8; ++n2)
                    accP[n2] = __builtin_amdgcn_mfma_f32_16x16x32_bf16(
                        bf[n2], a, accP[n2], 0, 0, 0);
            } else {
#pragma unroll
                for (int n2 = 0; n2 < 8; ++n2)
                    accQ[n2] = __builtin_amdgcn_mfma_f32_16x16x32_bf16(
                        bf[n2], a, accQ[n2], 0, 0, 0);
            }
        }
    }

    // ---- GRU epilogue -> xb[node] (accP=IN, accQ=HN) ----
    if (rowg >= M) return;
#pragma unroll
    for (int n2 = 0; n2 < 8; ++n2) {
        int col = n2 * 16 + lhi * 4;
        float4 bn = *(const float4*)&bias2[256 + col];
        float4 bh = *(const float4*)&bias2[384 + col];
        float4 hv = *(const float4*)&mem[(size_t)node * 128 + col];
        ushort4 o;
#pragma unroll
        for (int j = 0; j < 4; ++j) {
            float bN = (j == 0) ? bn.x : (j == 1) ? bn.y : (j == 2) ? bn.z : bn.w;
            float bH = (j == 0) ? bh.x : (j == 1) ? bh.y : (j == 2) ? bh.z : bh.w;
            float hj = (j == 0) ? hv.x : (j == 1) ? hv.y : (j == 2) ? hv.z : hv.w;
            unsigned p = rz[n2 * 4 + j];
            float r = b2f((u16)(p & 0xffff));
            float z = b2f((u16)(p >> 16));
            float n = tanhf(accP[n2][j] + bN + r * (accQ[n2][j] + bH));
            u16 res = f2b((1.f - z) * n + z * hj);
            if (j == 0) o.x = res; else if (j == 1) o.y = res;
            else if (j == 2) o.z = res; else o.w = res;
        }
        *(ushort4*)&xb[(size_t)node * 128 + col] = o;
    }
}

// ================= proj GEMM: r13/r15 pipeline, 3-buffer ring (LDS 64KB) =========
template <int K, int NQUAD>
__global__ __launch_bounds__(256, 1) void k_proj(
    const u16* __restrict__ A, const u16* __restrict__ Bp,
    const float* __restrict__ bias, int Mmax,
    u16* __restrict__ qb, u16* __restrict__ kb, u16* __restrict__ vcb,
    float* __restrict__ outf) {
    constexpr int KT = K / 64;          // 2
    constexpr int NT = NQUAD * KT;      // 12
    constexpr int NKS = K / 32;         // 4
    constexpr int CPR = K / 8;          // 16
    __shared__ u16 lA[64 * K];          // 16 KB
    __shared__ u16 lB[3][128 * 64];     // 48 KB ring

    const int tid = threadIdx.x;
    const int wid = tid >> 6, lane = tid & 63;
    const int lrow = lane & 15, lhi = lane >> 4;
    const int arow0 = blockIdx.x * 64;

#pragma unroll
    for (int i = 0; i < (64 * CPR) / 256; ++i) {
        int chunk = i * 256 + wid * 64 + lane;
        int row = chunk / CPR, cc = chunk % CPR;
        int ccs = (cc & ~7) | ((cc ^ row) & 7);
        gld_lds16(A + (size_t)(arow0 + row) * K + ccs * 8, &lA[(i * 256 + wid * 64) * 8]);
    }
    auto stTile = [&](int t) {
        int q = t / KT, kt = t - q * KT;
        u16* dst = (u16*)lB[t % 3];
#pragma unroll
        for (int i = 0; i < 4; ++i) {
            int chunk = i * 256 + wid * 64 + lane;
            int row = chunk >> 3, cc = chunk & 7;
            int ccs = cc ^ (row & 7);
            gld_lds16(Bp + (size_t)(q * 128 + row) * K + kt * 64 + ccs * 8,
                      &dst[(i * 256 + wid * 64) * 8]);
        }
    };
    stTile(0); stTile(1);
    // wait lA (oldest 4 of 12 outstanding) + barrier; 8 tile loads stay in flight
    asm volatile("s_waitcnt vmcnt(8)\ns_barrier" ::: "memory");
    __builtin_amdgcn_sched_barrier(0);

    bf16x8 af[NKS];
#pragma unroll
    for (int ks = 0; ks < NKS; ++ks) {
        int chunk = ks * 4 + lhi;
        int ccs = (chunk & ~7) | ((chunk ^ lrow) & 7);
        af[ks] = *(const bf16x8*)&lA[(size_t)(wid * 16 + lrow) * K + ccs * 8];
    }

    f32x4 acc[NQUAD][8] = {};
#pragma unroll
    for (int t = 0; t < NT; ++t) {
        if (t <= NT - 2) {
            asm volatile("s_waitcnt vmcnt(4)\ns_barrier" ::: "memory");
            __builtin_amdgcn_sched_barrier(0);
        } else {
            asm volatile("s_waitcnt vmcnt(0)\ns_barrier" ::: "memory");
            __builtin_amdgcn_sched_barrier(0);
        }
        if (t + 2 < NT) stTile(t + 2);
        const int q = t / KT, kt = t - q * KT;
        const u16* lBc = lB[t % 3];
#pragma unroll
        for (int ks = 0; ks < 2; ++ks) {
            bf16x8 bf[8];
#pragma unroll
            for (int n2 = 0; n2 < 8; ++n2) {
                int chunk = (ks * 4 + lhi) ^ (lrow & 7);
                bf[n2] = *(const bf16x8*)&lBc[(size_t)(n2 * 16 + lrow) * 64 + chunk * 8];
            }
#pragma unroll
            for (int n2 = 0; n2 < 8; ++n2)
                acc[q][n2] = __builtin_amdgcn_mfma_f32_16x16x32_bf16(
                    bf[n2], af[kt * 2 + ks], acc[q][n2], 0, 0, 0);
        }
    }

    const int rowg = arow0 + wid * 16 + lrow;
    if (rowg >= Mmax) return;

#pragma unroll
    for (int q = 0; q < NQUAD; ++q) {
#pragma unroll
        for (int n2 = 0; n2 < 8; ++n2) {
            int colg = q * 128 + n2 * 16 + lhi * 4;
            if (colg >= 704) continue;
            float4 bv = *(const float4*)&bias[colg];
            float v0 = acc[q][n2][0] + bv.x, v1 = acc[q][n2][1] + bv.y;
            float v2 = acc[q][n2][2] + bv.z, v3 = acc[q][n2][3] + bv.w;
            if (colg < 640) {
                ushort4 o;
                o.x = f2b(v0); o.y = f2b(v1); o.z = f2b(v2); o.w = f2b(v3);
                if (colg < 256)
                    *(ushort4*)&qb[(size_t)rowg * 256 + colg] = o;
                else if (colg < 512)
                    *(ushort4*)&kb[(size_t)rowg * 256 + (colg - 256)] = o;
                else
                    *(ushort4*)&vcb[(size_t)rowg * 128 + (colg - 512)] = o;
            } else {
                float4 o; o.x = v0; o.y = v1; o.z = v2; o.w = v3;
                *(float4*)&outf[(size_t)rowg * 64 + (colg - 640)] = o;
            }
        }
    }
}

// ---------------- CSR attention: one wave per dst, no atomics ----------------
__global__ __launch_bounds__(256) void k_attn(
    const u16* __restrict__ qB, const u16* __restrict__ kB, const u16* __restrict__ vcB,
    const int* __restrict__ startA, const int* __restrict__ deg,
    const int* __restrict__ esrc, float* __restrict__ out) {
    int wid = threadIdx.x >> 6, lane = threadIdx.x & 63;
    int dst = blockIdx.x * 4 + wid;
    if (dst >= N_NODES) return;
    int d = deg[dst];
    if (d == 0) return;
    int st = startA[dst];

    ushort4 qv = *(const ushort4*)&qB[(size_t)dst * 256 + lane * 4];
    float q0 = b2f(qv.x), q1 = b2f(qv.y), q2 = b2f(qv.z), q3 = b2f(qv.w);
    const float inv = 0.08838834764831845f;  // 1/sqrt(128)

    float s0 = 0.f, s1 = 0.f, accA = 0.f, accB = 0.f;
    int src = esrc[st];
    for (int p = st; p < st + d; ++p) {
        int src_next = (p + 1 < st + d) ? esrc[p + 1] : 0;
        ushort4 kv = *(const ushort4*)&kB[(size_t)src * 256 + lane * 4];
        float v0 = b2f(vcB[(size_t)src * 128 + lane]);
        float v1 = b2f(vcB[(size_t)src * 128 + 64 + lane]);
        float pp = q0 * b2f(kv.x) + q1 * b2f(kv.y) + q2 * b2f(kv.z) + q3 * b2f(kv.w);
        pp += __shfl_xor(pp, 1);
        pp += __shfl_xor(pp, 2);
        pp += __shfl_xor(pp, 4);
        pp += __shfl_xor(pp, 8);
        pp += __shfl_xor(pp, 16);
        float e = expf(pp * inv);
        float eo = __shfl_xor(e, 32);
        float e0 = (lane < 32) ? e : eo;
        float e1 = (lane < 32) ? eo : e;
        s0 += e0; s1 += e1;
        accA += e0 * v0;
        accB += e1 * v1;
        src = src_next;
    }
    float* op = out + (size_t)dst * 64 + lane;
    *op += accA / s0 + accB / s1;
}

extern "C" void kernel_launch(void* const* d_in, const int* in_sizes, int n_in,
                              void* d_out, int out_size, void* d_ws, size_t ws_size,
                              hipStream_t stream) {
    const float* memory = (const float*)d_in[0];
    const float* W1 = (const float*)d_in[1];  const float* b1 = (const float*)d_in[2];
    const float* W2 = (const float*)d_in[3];  const float* b2 = (const float*)d_in[4];
    const float* Wih = (const float*)d_in[5]; const float* Whh = (const float*)d_in[6];
    const float* bih = (const float*)d_in[7]; const float* bhh = (const float*)d_in[8];
    const float* Wq = (const float*)d_in[9];  const float* bq = (const float*)d_in[10];
    const float* Wk = (const float*)d_in[11]; const float* bk = (const float*)d_in[12];
    const float* Wv = (const float*)d_in[13]; const float* bv = (const float*)d_in[14];
    const float* Ws = (const float*)d_in[15]; const float* bs = (const float*)d_in[16];
    const float* Wc = (const float*)d_in[17]; const float* bc = (const float*)d_in[18];
    const float* eattr = (const float*)d_in[19];
    const int* ei = (const int*)d_in[21];
    float* out = (float*)d_out;

    char* ws = (char*)d_ws;
    size_t off = 0;
    auto alloc = [&](size_t bytes) -> char* {
        char* p = ws + off;
        off = (off + bytes + 255) & ~(size_t)255;
        return p;
    };
    u16* xb = (u16*)alloc((size_t)NPAD * 128 * 2);
    u16* qb = (u16*)alloc((size_t)NPAD * 256 * 2);
    u16* kb = (u16*)alloc((size_t)NPAD * 256 * 2);
    u16* vcb = (u16*)alloc((size_t)NPAD * 128 * 2);
    int* winner = (int*)alloc((size_t)N_NODES * 4);
    int* wnode = (int*)alloc((size_t)N_NODES * 4);
    int* wedge = (int*)alloc((size_t)N_NODES * 4);
    int* wsrc = (int*)alloc((size_t)N_NODES * 4);
    int* deg = (int*)alloc((size_t)N_NODES * 4);
    int* startA = (int*)alloc((size_t)N_NODES * 4);
    int* cursor = (int*)alloc((size_t)N_NODES * 4);
    int* esrc = (int*)alloc((size_t)E_EDGES * 4);
    int* counters = (int*)alloc(256);
    u16* W1p = (u16*)alloc(49152 * 2);
    u16* Wcat2p = (u16*)alloc(131072 * 2);
    u16* Wprojp = (u16*)alloc(98304 * 2);
    float* bias2 = (float*)alloc(512 * 4);
    float* bproj = (float*)alloc(768 * 4);
    (void)ws_size; (void)in_sizes; (void)n_in; (void)out_size;

    int* wcount = counters;  // counters[0]=wcount, counters[1]=etot

    hipLaunchKernelGGL(k_init, dim3(391), dim3(256), 0, stream, winner, deg, counters);
    hipLaunchKernelGGL(k_edges, dim3(1563), dim3(256), 0, stream, ei, winner, deg);
    hipLaunchKernelGGL(k_nodes, dim3(391), dim3(256), 0, stream,
                       winner, deg, ei, wnode, wedge, wsrc, counters, startA, cursor);
    hipLaunchKernelGGL(k_fill, dim3(1563), dim3(256), 0, stream, ei, cursor, esrc);
    hipLaunchKernelGGL(k_pack, dim3(579), dim3(256), 0, stream,
                       W1, Wq, Wk, Wv, Ws, Wc, bq, bk, bv, bs, bc, W1p, Wprojp, bproj);
    hipLaunchKernelGGL(k_fold, dim3(512), dim3(128), 0, stream,
                       W2, Wih, Whh, bih, bhh, b2, Wcat2p, bias2);
    hipLaunchKernelGGL(k_xinit, dim3(12500), dim3(256), 0, stream, memory, winner, xb);
    // fused gather + MLP + GRU for winner rows (512-thread, 2 row-groups)
    hipLaunchKernelGGL(k_mg, dim3(782), dim3(512), 0, stream,
                       memory, eattr, wnode, wedge, wsrc, wcount,
                       W1p, b1, Wcat2p, bias2, xb);
    // proj: [q|k|vc|skip] = xb @ Wproj + bproj  (skip -> out, f32)
    hipLaunchKernelGGL((k_proj<128, 6>), dim3(1564), dim3(256), 0, stream,
                       xb, Wprojp, bproj, N_NODES, qb, kb, vcb, out);
    // CSR attention: out[dst] += sum(alpha * vc[src]) per head, no atomics
    hipLaunchKernelGGL(k_attn, dim3(25000), dim3(256), 0, stream,
                       qb, kb, vcb, startA, deg, esrc, out);
}

// Round 17
// 381.421 us; speedup vs baseline: 1.1812x; 1.0152x over previous
//
#include <hip/hip_runtime.h>
#include <hip/hip_bf16.h>

#define N_NODES 100000
#define E_EDGES 400000
#define NPAD 100096   // 782 * 128

typedef unsigned short u16;
typedef __attribute__((ext_vector_type(4))) float f32x4;
typedef __attribute__((ext_vector_type(8))) short bf16x8;

__device__ inline u16 f2b(float v) {
    __hip_bfloat16 h = __float2bfloat16(v);
    return *reinterpret_cast<u16*>(&h);
}
__device__ inline float b2f(u16 u) { return __uint_as_float(((unsigned)u) << 16); }

__device__ inline void gld_lds16(const u16* g, u16* l) {
    __builtin_amdgcn_global_load_lds(
        (const __attribute__((address_space(1))) unsigned*)g,
        (__attribute__((address_space(3))) unsigned*)l, 16, 0, 0);
}

// ---------------- fold W2/b2 into Wcat: Wcat2p[512][256] bf16, bias2[512] f32 ----------
__global__ __launch_bounds__(128) void k_fold(
    const float* __restrict__ W2, const float* __restrict__ Wih,
    const float* __restrict__ Whh, const float* __restrict__ bih,
    const float* __restrict__ bhh, const float* __restrict__ b2,
    u16* __restrict__ Wcat2p, float* __restrict__ bias2) {
    int c = blockIdx.x, t = threadIdx.x;
    __shared__ float wrow[128];
    __shared__ float red[128];
    wrow[t] = (c < 384) ? Wih[c * 128 + t] : 0.f;
    __syncthreads();
    float a = 0.f;
    for (int m = 0; m < 128; ++m) a += W2[t * 128 + m] * wrow[m];
    Wcat2p[c * 256 + t] = f2b(a);
    float dv = (c < 256) ? Whh[c * 128 + t] : (c >= 384 ? Whh[(c - 128) * 128 + t] : 0.f);
    Wcat2p[c * 256 + 128 + t] = f2b(dv);
    red[t] = b2[t] * wrow[t];
    __syncthreads();
    for (int o = 64; o; o >>= 1) { if (t < o) red[t] += red[t + o]; __syncthreads(); }
    if (t == 0) {
        float b = (c < 256) ? bih[c] + bhh[c] + red[0]
                : (c < 384 ? bih[c] + red[0] : bhh[c - 128]);
        bias2[c] = b;
    }
}

// ---------------- pack W1 + proj weights (Wc-fold computed inline) ----------------
__global__ __launch_bounds__(256) void k_pack(
    const float* __restrict__ W1,
    const float* __restrict__ Wq, const float* __restrict__ Wk,
    const float* __restrict__ Wv, const float* __restrict__ Ws,
    const float* __restrict__ Wc,
    const float* __restrict__ bq, const float* __restrict__ bk,
    const float* __restrict__ bv, const float* __restrict__ bs,
    const float* __restrict__ bc,
    u16* __restrict__ W1p, u16* __restrict__ Wprojp, float* __restrict__ bproj) {
    int i = blockIdx.x * 256 + threadIdx.x;
    if (i < 49152) { int n = i / 384, k2 = i % 384; W1p[i] = f2b(W1[k2 * 128 + n]); return; }
    i -= 49152;
    if (i < 98304) {
        int n = i / 128, k2 = i % 128; float v;
        if (n < 256)      v = Wq[k2 * 256 + n];
        else if (n < 512) v = Wk[k2 * 256 + (n - 256)];
        else if (n < 640) {
            int t = n - 512, h = t >> 6, o = t & 63;
            float a = 0.f;
            for (int c = 0; c < 128; ++c) a += Wv[k2 * 256 + h * 128 + c] * Wc[(h * 128 + c) * 64 + o];
            v = a;
        } else if (n < 704) {
            int o = n - 640;
            float a = 0.f;
            for (int j = 0; j < 256; ++j) a += Ws[k2 * 256 + j] * Wc[j * 64 + o];
            v = a;
        } else v = 0.f;
        Wprojp[i] = f2b(v); return;
    }
    i -= 98304;
    if (i < 768) {
        float v;
        if (i < 256)      v = bq[i];
        else if (i < 512) v = bk[i - 256];
        else if (i < 640) {
            int t = i - 512, h = t >> 6, o = t & 63;
            float a = 0.f;
            for (int c = 0; c < 128; ++c) a += bv[h * 128 + c] * Wc[(h * 128 + c) * 64 + o];
            v = a;
        } else if (i < 704) {
            int o = i - 640;
            float a = bc[o];
            for (int j = 0; j < 256; ++j) a += bs[j] * Wc[j * 64 + o];
            v = a;
        } else v = 0.f;
        bproj[i] = v;
    }
}

// ---------------- init ----------------
__global__ void k_init(int* __restrict__ winner, int* __restrict__ deg,
                       int* __restrict__ counters) {
    int n = blockIdx.x * 256 + threadIdx.x;
    if (n == 0) { counters[0] = 0; counters[1] = 0; }  // wcount, etot
    if (n < N_NODES) { winner[n] = -1; deg[n] = 0; }
}

// ---------------- edge pass: winner (max edge idx) + degree histogram ----------------
__global__ void k_edges(const int* __restrict__ ei, int* __restrict__ winner,
                        int* __restrict__ deg) {
    int e = blockIdx.x * 256 + threadIdx.x;
    if (e < E_EDGES) {
        int dst = ei[E_EDGES + e];
        atomicMax(&winner[dst], e);
        atomicAdd(&deg[dst], 1);
    }
}

// -------- node pass: compact winners (node, edge, src triples) + CSR alloc --------
__global__ void k_nodes(const int* __restrict__ winner, const int* __restrict__ deg,
                        const int* __restrict__ ei,
                        int* __restrict__ wnode, int* __restrict__ wedge,
                        int* __restrict__ wsrc, int* __restrict__ counters,
                        int* __restrict__ startA, int* __restrict__ cursor) {
    int n = blockIdx.x * 256 + threadIdx.x;
    if (n >= N_NODES) return;
    int we = winner[n];
    if (we >= 0) {
        int i = atomicAdd(&counters[0], 1);
        wnode[i] = n;
        wedge[i] = we;
        wsrc[i] = ei[we];
    }
    int d = deg[n];
    int st = d ? atomicAdd(&counters[1], d) : 0;
    startA[n] = st;
    cursor[n] = st;
}

// ---------------- fill CSR: segment holds src node of each in-edge ----------------
__global__ void k_fill(const int* __restrict__ ei, int* __restrict__ cursor,
                       int* __restrict__ esrc) {
    int e = blockIdx.x * 256 + threadIdx.x;
    if (e < E_EDGES) {
        int dst = ei[E_EDGES + e];
        int pos = atomicAdd(&cursor[dst], 1);
        esrc[pos] = ei[e];
    }
}

// ---------------- x init (bf16 copy of memory; winner rows overwritten by k_mg) -------
__global__ void k_xinit(const float* __restrict__ mem, const int* __restrict__ winner,
                        u16* __restrict__ x) {
    size_t idx = ((size_t)blockIdx.x * 256 + threadIdx.x) * 4;
    if (idx >= (size_t)N_NODES * 128) return;
    if (winner[idx >> 7] >= 0) return;   // GRU will write this row
    float4 v = *(const float4*)(mem + idx);
    ushort4 o;
    o.x = f2b(v.x); o.y = f2b(v.y); o.z = f2b(v.z); o.w = f2b(v.w);
    *(ushort4*)(x + idx) = o;
}

// ========== fused gather + message-MLP + GRU for winner rows -> xb ==========
// r16 proven: 512-thread block = 2 row-groups x 4 waves sharing the SAME
// B-tile stream -> 8 waves/CU. 180 -> 116 us, no spill.
__global__ __launch_bounds__(512, 1) void k_mg(
    const float* __restrict__ mem, const float* __restrict__ eattr,
    const int* __restrict__ wnode, const int* __restrict__ wedge,
    const int* __restrict__ wsrc, const int* __restrict__ Mp,
    const u16* __restrict__ W1p, const float* __restrict__ b1,
    const u16* __restrict__ Wcat2p, const float* __restrict__ bias2,
    u16* __restrict__ xb) {
    __shared__ u16 lB[3][128 * 64];     // 48 KB ring (shared by both groups)
    __shared__ u16 h1l[2][64][136];     // 34.8 KB, padded rows, per group

    const int tid = threadIdx.x;
    const int wid = tid >> 6, lane = tid & 63;
    const int grp = wid >> 2, wv = wid & 3;
    const int lrow = lane & 15, lhi = lane >> 4;
    const int M = *Mp;
    const int arow0 = blockIdx.x * 128;
    if (arow0 >= M) return;

    const int rowg = arow0 + grp * 64 + wv * 16 + lrow;
    const int rowc = min(rowg, M - 1);
    const int node = wnode[rowc];
    const int we = wedge[rowc];
    const int src = wsrc[rowc];

    // gather A fragments FIRST (consumed by converts before staging loads matter)
    bf16x8 af[12];
#pragma unroll
    for (int ks = 0; ks < 12; ++ks) {
        int c = ks * 4 + lhi;
        const float* p;
        if (c < 16)      p = mem + (size_t)src * 128 + c * 8;
        else if (c < 32) p = mem + (size_t)node * 128 + (c - 16) * 8;
        else             p = eattr + (size_t)we * 128 + (c - 32) * 8;
        float4 v0 = *(const float4*)p;
        float4 v1 = *(const float4*)(p + 4);
        bf16x8 a;
        a[0] = (short)f2b(v0.x); a[1] = (short)f2b(v0.y);
        a[2] = (short)f2b(v0.z); a[3] = (short)f2b(v0.w);
        a[4] = (short)f2b(v1.x); a[5] = (short)f2b(v1.y);
        a[6] = (short)f2b(v1.z); a[7] = (short)f2b(v1.w);
        af[ks] = a;
    }

    // unified tile stream: t=0..5 -> W1p kt=t ; t=6..21 -> Wcat2p g=t-6
    auto stTile = [&](int t) {
        const u16* Bp; int K, rowoff, kt;
        if (t < 6) { Bp = W1p; K = 384; rowoff = 0; kt = t; }
        else { int g = t - 6; Bp = Wcat2p; K = 256; rowoff = (g >> 2) * 128; kt = g & 3; }
        u16* dst = (u16*)lB[t % 3];
#pragma unroll
        for (int i = 0; i < 2; ++i) {
            int chunk = i * 512 + wid * 64 + lane;
            int row = chunk >> 3, cc = chunk & 7;
            int ccs = cc ^ (row & 7);
            gld_lds16(Bp + (size_t)(rowoff + row) * K + kt * 64 + ccs * 8,
                      &dst[(i * 512 + wid * 64) * 8]);
        }
    };
    stTile(0); stTile(1);   // 4 loads/wave in flight (2 tiles)

    // ---- GEMM1: tiles 0..5, acc1 ----
    f32x4 acc1[8] = {};
#pragma unroll
    for (int t = 0; t < 6; ++t) {
        asm volatile("s_waitcnt vmcnt(2)\ns_barrier" ::: "memory");
        __builtin_amdgcn_sched_barrier(0);
        stTile(t + 2);
        const u16* lBc = lB[t % 3];
#pragma unroll
        for (int ks = 0; ks < 2; ++ks) {
            bf16x8 bf[8];
#pragma unroll
            for (int n2 = 0; n2 < 8; ++n2) {
                int chunk = (ks * 4 + lhi) ^ (lrow & 7);
                bf[n2] = *(const bf16x8*)&lBc[(size_t)(n2 * 16 + lrow) * 64 + chunk * 8];
            }
#pragma unroll
            for (int n2 = 0; n2 < 8; ++n2)
                acc1[n2] = __builtin_amdgcn_mfma_f32_16x16x32_bf16(
                    bf[n2], af[t * 2 + ks], acc1[n2], 0, 0, 0);
        }
    }

    // h1 -> LDS (per-group buffer; visibility via lgkmcnt(0) at PASS A entry)
    {
        const int rl = wv * 16 + lrow;
#pragma unroll
        for (int n2 = 0; n2 < 8; ++n2) {
            int col = n2 * 16 + lhi * 4;
            float4 bv = *(const float4*)&b1[col];
            ushort4 o;
            o.x = f2b(fmaxf(acc1[n2][0] + bv.x, 0.f));
            o.y = f2b(fmaxf(acc1[n2][1] + bv.y, 0.f));
            o.z = f2b(fmaxf(acc1[n2][2] + bv.z, 0.f));
            o.w = f2b(fmaxf(acc1[n2][3] + bv.w, 0.f));
            *(ushort4*)&h1l[grp][rl][col] = o;
        }
    }

    // ---- GEMM2 PASS A: global tiles 6..13 (quads 0,1 = R,Z) ----
    f32x4 accP[8] = {}, accQ[8] = {};
    bf16x8 af2[4];
#pragma unroll
    for (int tt = 0; tt < 8; ++tt) {
        if (tt == 0) {
            asm volatile("s_waitcnt vmcnt(2) lgkmcnt(0)\ns_barrier" ::: "memory");
            __builtin_amdgcn_sched_barrier(0);
        } else {
            asm volatile("s_waitcnt vmcnt(2)\ns_barrier" ::: "memory");
            __builtin_amdgcn_sched_barrier(0);
        }
        stTile(8 + tt);
        if (tt == 0) {
#pragma unroll
            for (int ks = 0; ks < 4; ++ks)
                af2[ks] = *(const bf16x8*)&h1l[grp][wv * 16 + lrow][ks * 32 + lhi * 8];
        }
        const u16* lBc = lB[(6 + tt) % 3];
#pragma unroll
        for (int ks = 0; ks < 2; ++ks) {
            const int kk = (tt & 3) * 2 + ks;
            bf16x8 a = (kk < 4) ? af2[kk] : af[kk];
            bf16x8 bf[8];
#pragma unroll
            for (int n2 = 0; n2 < 8; ++n2) {
                int chunk = (ks * 4 + lhi) ^ (lrow & 7);
                bf[n2] = *(const bf16x8*)&lBc[(size_t)(n2 * 16 + lrow) * 64 + chunk * 8];
            }
            if (tt < 4) {
#pragma unroll
                for (int n2 = 0; n2 < 8; ++n2)
                    accP[n2] = __builtin_amdgcn_mfma_f32_16x16x32_bf16(
                        bf[n2], a, accP[n2], 0, 0, 0);
            } else {
#pragma unroll
                for (int n2 = 0; n2 < 8; ++n2)
                    accQ[n2] = __builtin_amdgcn_mfma_f32_16x16x32_bf16(
                        bf[n2], a, accQ[n2], 0, 0, 0);
            }
        }
    }

    // ---- between passes: r = sigmoid(R), z = sigmoid(Z) -> packed bf16 pairs ----
    unsigned rz[32];
#pragma unroll
    for (int n2 = 0; n2 < 8; ++n2) {
        int col = n2 * 16 + lhi * 4;
        float4 br = *(const float4*)&bias2[col];
        float4 bz = *(const float4*)&bias2[128 + col];
#pragma unroll
        for (int j = 0; j < 4; ++j) {
            float bR = (j == 0) ? br.x : (j == 1) ? br.y : (j == 2) ? br.z : br.w;
            float bZ = (j == 0) ? bz.x : (j == 1) ? bz.y : (j == 2) ? bz.z : bz.w;
            float r = 1.f / (1.f + expf(-(accP[n2][j] + bR)));
            float z = 1.f / (1.f + expf(-(accQ[n2][j] + bZ)));
            rz[n2 * 4 + j] = (unsigned)f2b(r) | ((unsigned)f2b(z) << 16);
        }
        accP[n2] = (f32x4){0.f, 0.f, 0.f, 0.f};
        accQ[n2] = (f32x4){0.f, 0.f, 0.f, 0.f};
    }

    // ---- GEMM2 PASS B: global tiles 14..21 (quads 2,3 = IN,HN) ----
#pragma unroll
    for (int tt = 0; tt < 8; ++tt) {
        if (tt <= 6) {
            asm volatile("s_waitcnt vmcnt(2)\ns_barrier" ::: "memory");
            __builtin_amdgcn_sched_barrier(0);
        } else {
            asm volatile("s_waitcnt vmcnt(0)\ns_barrier" ::: "memory");
            __builtin_amdgcn_sched_barrier(0);
        }
        if (tt <= 5) stTile(16 + tt);
        const u16* lBc = lB[(14 + tt) % 3];
#pragma unroll
        for (int ks = 0; ks < 2; ++ks) {
            const int kk = (tt & 3) * 2 + ks;
            bf16x8 a = (kk < 4) ? af2[kk] : af[kk];
            bf16x8 bf[8];
#pragma unroll
            for (int n2 = 0; n2 < 8; ++n2) {
                int chunk = (ks * 4 + lhi) ^ (lrow & 7);
                bf[n2] = *(const bf16x8*)&lBc[(size_t)(n2 * 16 + lrow) * 64 + chunk * 8];
            }
            if (tt < 4) {
#pragma unroll
                for (int n2 = 0; n2 < 8; ++n2)
                    accP[n2] = __builtin_amdgcn_mfma_f32_16x16x32_bf16(
                        bf[n2], a, accP[n2], 0, 0, 0);
            } else {
#pragma unroll
                for (int n2 = 0; n2 < 8; ++n2)
                    accQ[n2] = __builtin_amdgcn_mfma_f32_16x16x32_bf16(
                        bf[n2], a, accQ[n2], 0, 0, 0);
            }
        }
    }

    // ---- GRU epilogue -> xb[node] (accP=IN, accQ=HN) ----
    if (rowg >= M) return;
#pragma unroll
    for (int n2 = 0; n2 < 8; ++n2) {
        int col = n2 * 16 + lhi * 4;
        float4 bn = *(const float4*)&bias2[256 + col];
        float4 bh = *(const float4*)&bias2[384 + col];
        float4 hv = *(const float4*)&mem[(size_t)node * 128 + col];
        ushort4 o;
#pragma unroll
        for (int j = 0; j < 4; ++j) {
            float bN = (j == 0) ? bn.x : (j == 1) ? bn.y : (j == 2) ? bn.z : bn.w;
            float bH = (j == 0) ? bh.x : (j == 1) ? bh.y : (j == 2) ? bh.z : bh.w;
            float hj = (j == 0) ? hv.x : (j == 1) ? hv.y : (j == 2) ? hv.z : hv.w;
            unsigned p = rz[n2 * 4 + j];
            float r = b2f((u16)(p & 0xffff));
            float z = b2f((u16)(p >> 16));
            float n = tanhf(accP[n2][j] + bN + r * (accQ[n2][j] + bH));
            u16 res = f2b((1.f - z) * n + z * hj);
            if (j == 0) o.x = res; else if (j == 1) o.y = res;
            else if (j == 2) o.z = res; else o.w = res;
        }
        *(ushort4*)&xb[(size_t)node * 128 + col] = o;
    }
}

// ===== proj GEMM: 512-thread, 2 row-groups x 4 waves sharing B-stream =====
// acc split into 2 passes of 3 quads (96 f32) so per-wave demand ~190 <= 256
// at 2 waves/SIMD. Per-group lA (2x16KB) + shared 48KB ring = 80 KB LDS.
// Two separately-unrolled pass loops + store between (r11 static-index rule).
__global__ __launch_bounds__(512, 1) void k_proj(
    const u16* __restrict__ A, const u16* __restrict__ Bp,
    const float* __restrict__ bias, int Mmax,
    u16* __restrict__ qb, u16* __restrict__ kb, u16* __restrict__ vcb,
    float* __restrict__ outf) {
    __shared__ u16 lA[2][64 * 128];     // 32 KB (per group)
    __shared__ u16 lB[3][128 * 64];     // 48 KB ring

    const int tid = threadIdx.x;
    const int wid = tid >> 6, lane = tid & 63;
    const int grp = wid >> 2, wv = wid & 3;
    const int lrow = lane & 15, lhi = lane >> 4;
    const int arow0 = blockIdx.x * 128;

    // each group's 4 waves stage their own lA (1024 chunks -> 4/thread)
#pragma unroll
    for (int i = 0; i < 4; ++i) {
        int chunk = i * 256 + wv * 64 + lane;
        int row = chunk >> 4, cc = chunk & 15;
        int ccs = (cc & ~7) | ((cc ^ row) & 7);
        gld_lds16(A + (size_t)(arow0 + grp * 64 + row) * 128 + ccs * 8,
                  &lA[grp][(i * 256 + wv * 64) * 8]);
    }
    auto stTile = [&](int t) {
        int q = t >> 1, kt = t & 1;
        u16* dst = (u16*)lB[t % 3];
#pragma unroll
        for (int i = 0; i < 2; ++i) {
            int chunk = i * 512 + wid * 64 + lane;
            int row = chunk >> 3, cc = chunk & 7;
            int ccs = cc ^ (row & 7);
            gld_lds16(Bp + (size_t)(q * 128 + row) * 128 + kt * 64 + ccs * 8,
                      &dst[(i * 512 + wid * 64) * 8]);
        }
    };
    stTile(0); stTile(1);
    // per-wave outstanding: 4 (lA) + 4 (tiles 0,1). Wait lA done -> vmcnt(4).
    asm volatile("s_waitcnt vmcnt(4)\ns_barrier" ::: "memory");
    __builtin_amdgcn_sched_barrier(0);

    bf16x8 af[4];
#pragma unroll
    for (int ks = 0; ks < 4; ++ks) {
        int chunk = ks * 4 + lhi;
        int ccs = (chunk & ~7) | ((chunk ^ lrow) & 7);
        af[ks] = *(const bf16x8*)&lA[grp][(size_t)(wv * 16 + lrow) * 128 + ccs * 8];
    }

    const int rowg = arow0 + grp * 64 + wv * 16 + lrow;
    auto storeq = [&](int q, f32x4 (&aq)[8]) {
        if (rowg >= Mmax) return;
#pragma unroll
        for (int n2 = 0; n2 < 8; ++n2) {
            int colg = q * 128 + n2 * 16 + lhi * 4;
            if (colg >= 704) continue;
            float4 bv = *(const float4*)&bias[colg];
            float v0 = aq[n2][0] + bv.x, v1 = aq[n2][1] + bv.y;
            float v2 = aq[n2][2] + bv.z, v3 = aq[n2][3] + bv.w;
            if (colg < 640) {
                ushort4 o;
                o.x = f2b(v0); o.y = f2b(v1); o.z = f2b(v2); o.w = f2b(v3);
                if (colg < 256)
                    *(ushort4*)&qb[(size_t)rowg * 256 + colg] = o;
                else if (colg < 512)
                    *(ushort4*)&kb[(size_t)rowg * 256 + (colg - 256)] = o;
                else
                    *(ushort4*)&vcb[(size_t)rowg * 128 + (colg - 512)] = o;
            } else {
                float4 o; o.x = v0; o.y = v1; o.z = v2; o.w = v3;
                *(float4*)&outf[(size_t)rowg * 64 + (colg - 640)] = o;
            }
        }
    };

    f32x4 accA[8] = {}, accB[8] = {}, accC[8] = {};
    // ---- PASS A: tiles 0..5 (quads 0,1,2) ----
#pragma unroll
    for (int t = 0; t < 6; ++t) {
        asm volatile("s_waitcnt vmcnt(2)\ns_barrier" ::: "memory");
        __builtin_amdgcn_sched_barrier(0);
        stTile(t + 2);
        const int qi = t >> 1;
        const u16* lBc = lB[t % 3];
#pragma unroll
        for (int ks = 0; ks < 2; ++ks) {
            bf16x8 bf[8];
#pragma unroll
            for (int n2 = 0; n2 < 8; ++n2) {
                int chunk = (ks * 4 + lhi) ^ (lrow & 7);
                bf[n2] = *(const bf16x8*)&lBc[(size_t)(n2 * 16 + lrow) * 64 + chunk * 8];
            }
            if (qi == 0) {
#pragma unroll
                for (int n2 = 0; n2 < 8; ++n2)
                    accA[n2] = __builtin_amdgcn_mfma_f32_16x16x32_bf16(
                        bf[n2], af[(t & 1) * 2 + ks], accA[n2], 0, 0, 0);
            } else if (qi == 1) {
#pragma unroll
                for (int n2 = 0; n2 < 8; ++n2)
                    accB[n2] = __builtin_amdgcn_mfma_f32_16x16x32_bf16(
                        bf[n2], af[(t & 1) * 2 + ks], accB[n2], 0, 0, 0);
            } else {
#pragma unroll
                for (int n2 = 0; n2 < 8; ++n2)
                    accC[n2] = __builtin_amdgcn_mfma_f32_16x16x32_bf16(
                        bf[n2], af[(t & 1) * 2 + ks], accC[n2], 0, 0, 0);
            }
        }
    }
    storeq(0, accA); storeq(1, accB); storeq(2, accC);
#pragma unroll
    for (int n2 = 0; n2 < 8; ++n2) {
        accA[n2] = (f32x4){0.f, 0.f, 0.f, 0.f};
        accB[n2] = (f32x4){0.f, 0.f, 0.f, 0.f};
        accC[n2] = (f32x4){0.f, 0.f, 0.f, 0.f};
    }

    // ---- PASS B: tiles 6..11 (quads 3,4,5) ----
#pragma unroll
    for (int tt = 0; tt < 6; ++tt) {
        if (tt <= 4) {
            asm volatile("s_waitcnt vmcnt(2)\ns_barrier" ::: "memory");
            __builtin_amdgcn_sched_barrier(0);
        } else {
            asm volatile("s_waitcnt vmcnt(0)\ns_barrier" ::: "memory");
            __builtin_amdgcn_sched_barrier(0);
        }
        if (tt <= 3) stTile(8 + tt);
        const int t = 6 + tt;
        const int qi = tt >> 1;
        const u16* lBc = lB[t % 3];
#pragma unroll
        for (int ks = 0; ks < 2; ++ks) {
            bf16x8 bf[8];
#pragma unroll
            for (int n2 = 0; n2 < 8; ++n2) {
                int chunk = (ks * 4 + lhi) ^ (lrow & 7);
                bf[n2] = *(const bf16x8*)&lBc[(size_t)(n2 * 16 + lrow) * 64 + chunk * 8];
            }
            if (qi == 0) {
#pragma unroll
                for (int n2 = 0; n2 < 8; ++n2)
                    accA[n2] = __builtin_amdgcn_mfma_f32_16x16x32_bf16(
                        bf[n2], af[(tt & 1) * 2 + ks], accA[n2], 0, 0, 0);
            } else if (qi == 1) {
#pragma unroll
                for (int n2 = 0; n2 < 8; ++n2)
                    accB[n2] = __builtin_amdgcn_mfma_f32_16x16x32_bf16(
                        bf[n2], af[(tt & 1) * 2 + ks], accB[n2], 0, 0, 0);
            } else {
#pragma unroll
                for (int n2 = 0; n2 < 8; ++n2)
                    accC[n2] = __builtin_amdgcn_mfma_f32_16x16x32_bf16(
                        bf[n2], af[(tt & 1) * 2 + ks], accC[n2], 0, 0, 0);
            }
        }
    }
    storeq(3, accA); storeq(4, accB); storeq(5, accC);
}

// ---------------- CSR attention: one wave per dst, no atomics ----------------
__global__ __launch_bounds__(256) void k_attn(
    const u16* __restrict__ qB, const u16* __restrict__ kB, const u16* __restrict__ vcB,
    const int* __restrict__ startA, const int* __restrict__ deg,
    const int* __restrict__ esrc, float* __restrict__ out) {
    int wid = threadIdx.x >> 6, lane = threadIdx.x & 63;
    int dst = blockIdx.x * 4 + wid;
    if (dst >= N_NODES) return;
    int d = deg[dst];
    if (d == 0) return;
    int st = startA[dst];

    ushort4 qv = *(const ushort4*)&qB[(size_t)dst * 256 + lane * 4];
    float q0 = b2f(qv.x), q1 = b2f(qv.y), q2 = b2f(qv.z), q3 = b2f(qv.w);
    const float inv = 0.08838834764831845f;  // 1/sqrt(128)

    float s0 = 0.f, s1 = 0.f, accA = 0.f, accB = 0.f;
    int src = esrc[st];
    for (int p = st; p < st + d; ++p) {
        int src_next = (p + 1 < st + d) ? esrc[p + 1] : 0;
        ushort4 kv = *(const ushort4*)&kB[(size_t)src * 256 + lane * 4];
        float v0 = b2f(vcB[(size_t)src * 128 + lane]);
        float v1 = b2f(vcB[(size_t)src * 128 + 64 + lane]);
        float pp = q0 * b2f(kv.x) + q1 * b2f(kv.y) + q2 * b2f(kv.z) + q3 * b2f(kv.w);
        pp += __shfl_xor(pp, 1);
        pp += __shfl_xor(pp, 2);
        pp += __shfl_xor(pp, 4);
        pp += __shfl_xor(pp, 8);
        pp += __shfl_xor(pp, 16);
        float e = expf(pp * inv);
        float eo = __shfl_xor(e, 32);
        float e0 = (lane < 32) ? e : eo;
        float e1 = (lane < 32) ? eo : e;
        s0 += e0; s1 += e1;
        accA += e0 * v0;
        accB += e1 * v1;
        src = src_next;
    }
    float* op = out + (size_t)dst * 64 + lane;
    *op += accA / s0 + accB / s1;
}

extern "C" void kernel_launch(void* const* d_in, const int* in_sizes, int n_in,
                              void* d_out, int out_size, void* d_ws, size_t ws_size,
                              hipStream_t stream) {
    const float* memory = (const float*)d_in[0];
    const float* W1 = (const float*)d_in[1];  const float* b1 = (const float*)d_in[2];
    const float* W2 = (const float*)d_in[3];  const float* b2 = (const float*)d_in[4];
    const float* Wih = (const float*)d_in[5]; const float* Whh = (const float*)d_in[6];
    const float* bih = (const float*)d_in[7]; const float* bhh = (const float*)d_in[8];
    const float* Wq = (const float*)d_in[9];  const float* bq = (const float*)d_in[10];
    const float* Wk = (const float*)d_in[11]; const float* bk = (const float*)d_in[12];
    const float* Wv = (const float*)d_in[13]; const float* bv = (const float*)d_in[14];
    const float* Ws = (const float*)d_in[15]; const float* bs = (const float*)d_in[16];
    const float* Wc = (const float*)d_in[17]; const float* bc = (const float*)d_in[18];
    const float* eattr = (const float*)d_in[19];
    const int* ei = (const int*)d_in[21];
    float* out = (float*)d_out;

    char* ws = (char*)d_ws;
    size_t off = 0;
    auto alloc = [&](size_t bytes) -> char* {
        char* p = ws + off;
        off = (off + bytes + 255) & ~(size_t)255;
        return p;
    };
    u16* xb = (u16*)alloc((size_t)NPAD * 128 * 2);
    u16* qb = (u16*)alloc((size_t)NPAD * 256 * 2);
    u16* kb = (u16*)alloc((size_t)NPAD * 256 * 2);
    u16* vcb = (u16*)alloc((size_t)NPAD * 128 * 2);
    int* winner = (int*)alloc((size_t)N_NODES * 4);
    int* wnode = (int*)alloc((size_t)N_NODES * 4);
    int* wedge = (int*)alloc((size_t)N_NODES * 4);
    int* wsrc = (int*)alloc((size_t)N_NODES * 4);
    int* deg = (int*)alloc((size_t)N_NODES * 4);
    int* startA = (int*)alloc((size_t)N_NODES * 4);
    int* cursor = (int*)alloc((size_t)N_NODES * 4);
    int* esrc = (int*)alloc((size_t)E_EDGES * 4);
    int* counters = (int*)alloc(256);
    u16* W1p = (u16*)alloc(49152 * 2);
    u16* Wcat2p = (u16*)alloc(131072 * 2);
    u16* Wprojp = (u16*)alloc(98304 * 2);
    float* bias2 = (float*)alloc(512 * 4);
    float* bproj = (float*)alloc(768 * 4);
    (void)ws_size; (void)in_sizes; (void)n_in; (void)out_size;

    int* wcount = counters;  // counters[0]=wcount, counters[1]=etot

    hipLaunchKernelGGL(k_init, dim3(391), dim3(256), 0, stream, winner, deg, counters);
    hipLaunchKernelGGL(k_edges, dim3(1563), dim3(256), 0, stream, ei, winner, deg);
    hipLaunchKernelGGL(k_nodes, dim3(391), dim3(256), 0, stream,
                       winner, deg, ei, wnode, wedge, wsrc, counters, startA, cursor);
    hipLaunchKernelGGL(k_fill, dim3(1563), dim3(256), 0, stream, ei, cursor, esrc);
    hipLaunchKernelGGL(k_pack, dim3(579), dim3(256), 0, stream,
                       W1, Wq, Wk, Wv, Ws, Wc, bq, bk, bv, bs, bc, W1p, Wprojp, bproj);
    hipLaunchKernelGGL(k_fold, dim3(512), dim3(128), 0, stream,
                       W2, Wih, Whh, bih, bhh, b2, Wcat2p, bias2);
    hipLaunchKernelGGL(k_xinit, dim3(12500), dim3(256), 0, stream, memory, winner, xb);
    // fused gather + MLP + GRU for winner rows (512-thread, 2 row-groups)
    hipLaunchKernelGGL(k_mg, dim3(782), dim3(512), 0, stream,
                       memory, eattr, wnode, wedge, wsrc, wcount,
                       W1p, b1, Wcat2p, bias2, xb);
    // proj: [q|k|vc|skip] = xb @ Wproj + bproj  (512-thread, 2 row-groups)
    hipLaunchKernelGGL(k_proj, dim3(782), dim3(512), 0, stream,
                       xb, Wprojp, bproj, N_NODES, qb, kb, vcb, out);
    // CSR attention: out[dst] += sum(alpha * vc[src]) per head, no atomics
    hipLaunchKernelGGL(k_attn, dim3(25000), dim3(256), 0, stream,
                       qb, kb, vcb, startA, deg, esrc, out);
}

// Round 18
// 368.078 us; speedup vs baseline: 1.2240x; 1.0363x over previous
//
#include <hip/hip_runtime.h>
#include <hip/hip_bf16.h>

#define N_NODES 100000
#define E_EDGES 400000
#define NPAD 100096   // 782 * 128

typedef unsigned short u16;
typedef __attribute__((ext_vector_type(4))) float f32x4;
typedef __attribute__((ext_vector_type(8))) short bf16x8;

__device__ inline u16 f2b(float v) {
    __hip_bfloat16 h = __float2bfloat16(v);
    return *reinterpret_cast<u16*>(&h);
}
__device__ inline float b2f(u16 u) { return __uint_as_float(((unsigned)u) << 16); }

__device__ inline void gld_lds16(const u16* g, u16* l) {
    __builtin_amdgcn_global_load_lds(
        (const __attribute__((address_space(1))) unsigned*)g,
        (__attribute__((address_space(3))) unsigned*)l, 16, 0, 0);
}

// ---------------- fold W2/b2 into Wcat: Wcat2p[512][256] bf16, bias2[512] f32 ----------
__global__ __launch_bounds__(128) void k_fold(
    const float* __restrict__ W2, const float* __restrict__ Wih,
    const float* __restrict__ Whh, const float* __restrict__ bih,
    const float* __restrict__ bhh, const float* __restrict__ b2,
    u16* __restrict__ Wcat2p, float* __restrict__ bias2) {
    int c = blockIdx.x, t = threadIdx.x;
    __shared__ float wrow[128];
    __shared__ float red[128];
    wrow[t] = (c < 384) ? Wih[c * 128 + t] : 0.f;
    __syncthreads();
    float a = 0.f;
    for (int m = 0; m < 128; ++m) a += W2[t * 128 + m] * wrow[m];
    Wcat2p[c * 256 + t] = f2b(a);
    float dv = (c < 256) ? Whh[c * 128 + t] : (c >= 384 ? Whh[(c - 128) * 128 + t] : 0.f);
    Wcat2p[c * 256 + 128 + t] = f2b(dv);
    red[t] = b2[t] * wrow[t];
    __syncthreads();
    for (int o = 64; o; o >>= 1) { if (t < o) red[t] += red[t + o]; __syncthreads(); }
    if (t == 0) {
        float b = (c < 256) ? bih[c] + bhh[c] + red[0]
                : (c < 384 ? bih[c] + red[0] : bhh[c - 128]);
        bias2[c] = b;
    }
}

// ---------------- pack W1 + proj weights (Wc-fold computed inline) ----------------
__global__ __launch_bounds__(256) void k_pack(
    const float* __restrict__ W1,
    const float* __restrict__ Wq, const float* __restrict__ Wk,
    const float* __restrict__ Wv, const float* __restrict__ Ws,
    const float* __restrict__ Wc,
    const float* __restrict__ bq, const float* __restrict__ bk,
    const float* __restrict__ bv, const float* __restrict__ bs,
    const float* __restrict__ bc,
    u16* __restrict__ W1p, u16* __restrict__ Wprojp, float* __restrict__ bproj) {
    int i = blockIdx.x * 256 + threadIdx.x;
    if (i < 49152) { int n = i / 384, k2 = i % 384; W1p[i] = f2b(W1[k2 * 128 + n]); return; }
    i -= 49152;
    if (i < 98304) {
        int n = i / 128, k2 = i % 128; float v;
        if (n < 256)      v = Wq[k2 * 256 + n];
        else if (n < 512) v = Wk[k2 * 256 + (n - 256)];
        else if (n < 640) {
            int t = n - 512, h = t >> 6, o = t & 63;
            float a = 0.f;
            for (int c = 0; c < 128; ++c) a += Wv[k2 * 256 + h * 128 + c] * Wc[(h * 128 + c) * 64 + o];
            v = a;
        } else if (n < 704) {
            int o = n - 640;
            float a = 0.f;
            for (int j = 0; j < 256; ++j) a += Ws[k2 * 256 + j] * Wc[j * 64 + o];
            v = a;
        } else v = 0.f;
        Wprojp[i] = f2b(v); return;
    }
    i -= 98304;
    if (i < 768) {
        float v;
        if (i < 256)      v = bq[i];
        else if (i < 512) v = bk[i - 256];
        else if (i < 640) {
            int t = i - 512, h = t >> 6, o = t & 63;
            float a = 0.f;
            for (int c = 0; c < 128; ++c) a += bv[h * 128 + c] * Wc[(h * 128 + c) * 64 + o];
            v = a;
        } else if (i < 704) {
            int o = i - 640;
            float a = bc[o];
            for (int j = 0; j < 256; ++j) a += bs[j] * Wc[j * 64 + o];
            v = a;
        } else v = 0.f;
        bproj[i] = v;
    }
}

// ---------------- init ----------------
__global__ void k_init(int* __restrict__ winner, int* __restrict__ deg,
                       int* __restrict__ counters) {
    int n = blockIdx.x * 256 + threadIdx.x;
    if (n == 0) { counters[0] = 0; counters[1] = 0; }  // wcount, etot
    if (n < N_NODES) { winner[n] = -1; deg[n] = 0; }
}

// ---------------- edge pass: winner (max edge idx) + degree histogram ----------------
__global__ void k_edges(const int* __restrict__ ei, int* __restrict__ winner,
                        int* __restrict__ deg) {
    int e = blockIdx.x * 256 + threadIdx.x;
    if (e < E_EDGES) {
        int dst = ei[E_EDGES + e];
        atomicMax(&winner[dst], e);
        atomicAdd(&deg[dst], 1);
    }
}

// -------- node pass: compact winners (node, edge, src triples) + CSR alloc --------
__global__ void k_nodes(const int* __restrict__ winner, const int* __restrict__ deg,
                        const int* __restrict__ ei,
                        int* __restrict__ wnode, int* __restrict__ wedge,
                        int* __restrict__ wsrc, int* __restrict__ counters,
                        int* __restrict__ startA, int* __restrict__ cursor) {
    int n = blockIdx.x * 256 + threadIdx.x;
    if (n >= N_NODES) return;
    int we = winner[n];
    if (we >= 0) {
        int i = atomicAdd(&counters[0], 1);
        wnode[i] = n;
        wedge[i] = we;
        wsrc[i] = ei[we];
    }
    int d = deg[n];
    int st = d ? atomicAdd(&counters[1], d) : 0;
    startA[n] = st;
    cursor[n] = st;
}

// ---------------- fill CSR: segment holds src node of each in-edge ----------------
__global__ void k_fill(const int* __restrict__ ei, int* __restrict__ cursor,
                       int* __restrict__ esrc) {
    int e = blockIdx.x * 256 + threadIdx.x;
    if (e < E_EDGES) {
        int dst = ei[E_EDGES + e];
        int pos = atomicAdd(&cursor[dst], 1);
        esrc[pos] = ei[e];
    }
}

// ---------------- x init (bf16 copy of memory; winner rows overwritten by k_mg) -------
__global__ void k_xinit(const float* __restrict__ mem, const int* __restrict__ winner,
                        u16* __restrict__ x) {
    size_t idx = ((size_t)blockIdx.x * 256 + threadIdx.x) * 4;
    if (idx >= (size_t)N_NODES * 128) return;
    if (winner[idx >> 7] >= 0) return;   // GRU will write this row
    float4 v = *(const float4*)(mem + idx);
    ushort4 o;
    o.x = f2b(v.x); o.y = f2b(v.y); o.z = f2b(v.z); o.w = f2b(v.w);
    *(ushort4*)(x + idx) = o;
}

// ========== fused gather + message-MLP + GRU for winner rows -> xb ==========
// r16 proven 512-thread 2-row-group structure + 4-buffer ring (3 tiles in
// flight, vmcnt(4) steady waits). LDS 64+34.8 = 98.8 KB (fits 1 blk/CU).
__global__ __launch_bounds__(512, 1) void k_mg(
    const float* __restrict__ mem, const float* __restrict__ eattr,
    const int* __restrict__ wnode, const int* __restrict__ wedge,
    const int* __restrict__ wsrc, const int* __restrict__ Mp,
    const u16* __restrict__ W1p, const float* __restrict__ b1,
    const u16* __restrict__ Wcat2p, const float* __restrict__ bias2,
    u16* __restrict__ xb) {
    __shared__ u16 lB[4][128 * 64];     // 64 KB ring (shared by both groups)
    __shared__ u16 h1l[2][64][136];     // 34.8 KB, padded rows, per group

    const int tid = threadIdx.x;
    const int wid = tid >> 6, lane = tid & 63;
    const int grp = wid >> 2, wv = wid & 3;
    const int lrow = lane & 15, lhi = lane >> 4;
    const int M = *Mp;
    const int arow0 = blockIdx.x * 128;
    if (arow0 >= M) return;

    const int rowg = arow0 + grp * 64 + wv * 16 + lrow;
    const int rowc = min(rowg, M - 1);
    const int node = wnode[rowc];
    const int we = wedge[rowc];
    const int src = wsrc[rowc];

    // gather A fragments FIRST (consumed by converts before staging loads matter)
    bf16x8 af[12];
#pragma unroll
    for (int ks = 0; ks < 12; ++ks) {
        int c = ks * 4 + lhi;
        const float* p;
        if (c < 16)      p = mem + (size_t)src * 128 + c * 8;
        else if (c < 32) p = mem + (size_t)node * 128 + (c - 16) * 8;
        else             p = eattr + (size_t)we * 128 + (c - 32) * 8;
        float4 v0 = *(const float4*)p;
        float4 v1 = *(const float4*)(p + 4);
        bf16x8 a;
        a[0] = (short)f2b(v0.x); a[1] = (short)f2b(v0.y);
        a[2] = (short)f2b(v0.z); a[3] = (short)f2b(v0.w);
        a[4] = (short)f2b(v1.x); a[5] = (short)f2b(v1.y);
        a[6] = (short)f2b(v1.z); a[7] = (short)f2b(v1.w);
        af[ks] = a;
    }

    // unified tile stream: t=0..5 -> W1p kt=t ; t=6..21 -> Wcat2p g=t-6
    auto stTile = [&](int t) {
        const u16* Bp; int K, rowoff, kt;
        if (t < 6) { Bp = W1p; K = 384; rowoff = 0; kt = t; }
        else { int g = t - 6; Bp = Wcat2p; K = 256; rowoff = (g >> 2) * 128; kt = g & 3; }
        u16* dst = (u16*)lB[t & 3];
#pragma unroll
        for (int i = 0; i < 2; ++i) {
            int chunk = i * 512 + wid * 64 + lane;
            int row = chunk >> 3, cc = chunk & 7;
            int ccs = cc ^ (row & 7);
            gld_lds16(Bp + (size_t)(rowoff + row) * K + kt * 64 + ccs * 8,
                      &dst[(i * 512 + wid * 64) * 8]);
        }
    };
    stTile(0); stTile(1); stTile(2);   // 6 loads/wave in flight (3 tiles)

    // ---- GEMM1: tiles 0..5, acc1 ----
    f32x4 acc1[8] = {};
#pragma unroll
    for (int t = 0; t < 6; ++t) {
        asm volatile("s_waitcnt vmcnt(4)\ns_barrier" ::: "memory");
        __builtin_amdgcn_sched_barrier(0);
        stTile(t + 3);
        const u16* lBc = lB[t & 3];
#pragma unroll
        for (int ks = 0; ks < 2; ++ks) {
            bf16x8 bf[8];
#pragma unroll
            for (int n2 = 0; n2 < 8; ++n2) {
                int chunk = (ks * 4 + lhi) ^ (lrow & 7);
                bf[n2] = *(const bf16x8*)&lBc[(size_t)(n2 * 16 + lrow) * 64 + chunk * 8];
            }
#pragma unroll
            for (int n2 = 0; n2 < 8; ++n2)
                acc1[n2] = __builtin_amdgcn_mfma_f32_16x16x32_bf16(
                    bf[n2], af[t * 2 + ks], acc1[n2], 0, 0, 0);
        }
    }

    // h1 -> LDS (per-group buffer; visibility via lgkmcnt(0) at PASS A entry)
    {
        const int rl = wv * 16 + lrow;
#pragma unroll
        for (int n2 = 0; n2 < 8; ++n2) {
            int col = n2 * 16 + lhi * 4;
            float4 bv = *(const float4*)&b1[col];
            ushort4 o;
            o.x = f2b(fmaxf(acc1[n2][0] + bv.x, 0.f));
            o.y = f2b(fmaxf(acc1[n2][1] + bv.y, 0.f));
            o.z = f2b(fmaxf(acc1[n2][2] + bv.z, 0.f));
            o.w = f2b(fmaxf(acc1[n2][3] + bv.w, 0.f));
            *(ushort4*)&h1l[grp][rl][col] = o;
        }
    }

    // ---- GEMM2 PASS A: global tiles 6..13 (quads 0,1 = R,Z) ----
    f32x4 accP[8] = {}, accQ[8] = {};
    bf16x8 af2[4];
#pragma unroll
    for (int tt = 0; tt < 8; ++tt) {
        if (tt == 0) {
            asm volatile("s_waitcnt vmcnt(4) lgkmcnt(0)\ns_barrier" ::: "memory");
            __builtin_amdgcn_sched_barrier(0);
        } else {
            asm volatile("s_waitcnt vmcnt(4)\ns_barrier" ::: "memory");
            __builtin_amdgcn_sched_barrier(0);
        }
        stTile(9 + tt);
        if (tt == 0) {
#pragma unroll
            for (int ks = 0; ks < 4; ++ks)
                af2[ks] = *(const bf16x8*)&h1l[grp][wv * 16 + lrow][ks * 32 + lhi * 8];
        }
        const u16* lBc = lB[(6 + tt) & 3];
#pragma unroll
        for (int ks = 0; ks < 2; ++ks) {
            const int kk = (tt & 3) * 2 + ks;
            bf16x8 a = (kk < 4) ? af2[kk] : af[kk];
            bf16x8 bf[8];
#pragma unroll
            for (int n2 = 0; n2 < 8; ++n2) {
                int chunk = (ks * 4 + lhi) ^ (lrow & 7);
                bf[n2] = *(const bf16x8*)&lBc[(size_t)(n2 * 16 + lrow) * 64 + chunk * 8];
            }
            if (tt < 4) {
#pragma unroll
                for (int n2 = 0; n2 < 8; ++n2)
                    accP[n2] = __builtin_amdgcn_mfma_f32_16x16x32_bf16(
                        bf[n2], a, accP[n2], 0, 0, 0);
            } else {
#pragma unroll
                for (int n2 = 0; n2 < 8; ++n2)
                    accQ[n2] = __builtin_amdgcn_mfma_f32_16x16x32_bf16(
                        bf[n2], a, accQ[n2], 0, 0, 0);
            }
        }
    }

    // ---- between passes: r = sigmoid(R), z = sigmoid(Z) -> packed bf16 pairs ----
    unsigned rz[32];
#pragma unroll
    for (int n2 = 0; n2 < 8; ++n2) {
        int col = n2 * 16 + lhi * 4;
        float4 br = *(const float4*)&bias2[col];
        float4 bz = *(const float4*)&bias2[128 + col];
#pragma unroll
        for (int j = 0; j < 4; ++j) {
            float bR = (j == 0) ? br.x : (j == 1) ? br.y : (j == 2) ? br.z : br.w;
            float bZ = (j == 0) ? bz.x : (j == 1) ? bz.y : (j == 2) ? bz.z : bz.w;
            float r = 1.f / (1.f + __expf(-(accP[n2][j] + bR)));
            float z = 1.f / (1.f + __expf(-(accQ[n2][j] + bZ)));
            rz[n2 * 4 + j] = (unsigned)f2b(r) | ((unsigned)f2b(z) << 16);
        }
        accP[n2] = (f32x4){0.f, 0.f, 0.f, 0.f};
        accQ[n2] = (f32x4){0.f, 0.f, 0.f, 0.f};
    }

    // ---- GEMM2 PASS B: global tiles 14..21 (quads 2,3 = IN,HN) ----
#pragma unroll
    for (int tt = 0; tt < 8; ++tt) {
        if (tt <= 5) {
            asm volatile("s_waitcnt vmcnt(4)\ns_barrier" ::: "memory");
            __builtin_amdgcn_sched_barrier(0);
        } else if (tt == 6) {
            asm volatile("s_waitcnt vmcnt(2)\ns_barrier" ::: "memory");
            __builtin_amdgcn_sched_barrier(0);
        } else {
            asm volatile("s_waitcnt vmcnt(0)\ns_barrier" ::: "memory");
            __builtin_amdgcn_sched_barrier(0);
        }
        if (tt <= 4) stTile(17 + tt);
        const u16* lBc = lB[(14 + tt) & 3];
#pragma unroll
        for (int ks = 0; ks < 2; ++ks) {
            const int kk = (tt & 3) * 2 + ks;
            bf16x8 a = (kk < 4) ? af2[kk] : af[kk];
            bf16x8 bf[8];
#pragma unroll
            for (int n2 = 0; n2 < 8; ++n2) {
                int chunk = (ks * 4 + lhi) ^ (lrow & 7);
                bf[n2] = *(const bf16x8*)&lBc[(size_t)(n2 * 16 + lrow) * 64 + chunk * 8];
            }
            if (tt < 4) {
#pragma unroll
                for (int n2 = 0; n2 < 8; ++n2)
                    accP[n2] = __builtin_amdgcn_mfma_f32_16x16x32_bf16(
                        bf[n2], a, accP[n2], 0, 0, 0);
            } else {
#pragma unroll
                for (int n2 = 0; n2 < 8; ++n2)
                    accQ[n2] = __builtin_amdgcn_mfma_f32_16x16x32_bf16(
                        bf[n2], a, accQ[n2], 0, 0, 0);
            }
        }
    }

    // ---- GRU epilogue -> xb[node] (accP=IN, accQ=HN) ----
    if (rowg >= M) return;
#pragma unroll
    for (int n2 = 0; n2 < 8; ++n2) {
        int col = n2 * 16 + lhi * 4;
        float4 bn = *(const float4*)&bias2[256 + col];
        float4 bh = *(const float4*)&bias2[384 + col];
        float4 hv = *(const float4*)&mem[(size_t)node * 128 + col];
        ushort4 o;
#pragma unroll
        for (int j = 0; j < 4; ++j) {
            float bN = (j == 0) ? bn.x : (j == 1) ? bn.y : (j == 2) ? bn.z : bn.w;
            float bH = (j == 0) ? bh.x : (j == 1) ? bh.y : (j == 2) ? bh.z : bh.w;
            float hj = (j == 0) ? hv.x : (j == 1) ? hv.y : (j == 2) ? hv.z : hv.w;
            unsigned p = rz[n2 * 4 + j];
            float r = b2f((u16)(p & 0xffff));
            float z = b2f((u16)(p >> 16));
            float n = tanhf(accP[n2][j] + bN + r * (accQ[n2][j] + bH));
            u16 res = f2b((1.f - z) * n + z * hj);
            if (j == 0) o.x = res; else if (j == 1) o.y = res;
            else if (j == 2) o.z = res; else o.w = res;
        }
        *(ushort4*)&xb[(size_t)node * 128 + col] = o;
    }
}

// ===== proj GEMM: 512-thread, 2 row-groups, 4-buffer ring (LDS 96 KB) =====
__global__ __launch_bounds__(512, 1) void k_proj(
    const u16* __restrict__ A, const u16* __restrict__ Bp,
    const float* __restrict__ bias, int Mmax,
    u16* __restrict__ qb, u16* __restrict__ kb, u16* __restrict__ vcb,
    float* __restrict__ outf) {
    __shared__ u16 lA[2][64 * 128];     // 32 KB (per group)
    __shared__ u16 lB[4][128 * 64];     // 64 KB ring

    const int tid = threadIdx.x;
    const int wid = tid >> 6, lane = tid & 63;
    const int grp = wid >> 2, wv = wid & 3;
    const int lrow = lane & 15, lhi = lane >> 4;
    const int arow0 = blockIdx.x * 128;

    // each group's 4 waves stage their own lA (1024 chunks -> 4/thread)
#pragma unroll
    for (int i = 0; i < 4; ++i) {
        int chunk = i * 256 + wv * 64 + lane;
        int row = chunk >> 4, cc = chunk & 15;
        int ccs = (cc & ~7) | ((cc ^ row) & 7);
        gld_lds16(A + (size_t)(arow0 + grp * 64 + row) * 128 + ccs * 8,
                  &lA[grp][(i * 256 + wv * 64) * 8]);
    }
    auto stTile = [&](int t) {
        int q = t >> 1, kt = t & 1;
        u16* dst = (u16*)lB[t & 3];
#pragma unroll
        for (int i = 0; i < 2; ++i) {
            int chunk = i * 512 + wid * 64 + lane;
            int row = chunk >> 3, cc = chunk & 7;
            int ccs = cc ^ (row & 7);
            gld_lds16(Bp + (size_t)(q * 128 + row) * 128 + kt * 64 + ccs * 8,
                      &dst[(i * 512 + wid * 64) * 8]);
        }
    };
    stTile(0); stTile(1); stTile(2);
    // per-wave outstanding: 4 (lA) + 6 (tiles 0..2). Wait lA done -> vmcnt(6).
    asm volatile("s_waitcnt vmcnt(6)\ns_barrier" ::: "memory");
    __builtin_amdgcn_sched_barrier(0);

    bf16x8 af[4];
#pragma unroll
    for (int ks = 0; ks < 4; ++ks) {
        int chunk = ks * 4 + lhi;
        int ccs = (chunk & ~7) | ((chunk ^ lrow) & 7);
        af[ks] = *(const bf16x8*)&lA[grp][(size_t)(wv * 16 + lrow) * 128 + ccs * 8];
    }

    const int rowg = arow0 + grp * 64 + wv * 16 + lrow;
    auto storeq = [&](int q, f32x4 (&aq)[8]) {
        if (rowg >= Mmax) return;
#pragma unroll
        for (int n2 = 0; n2 < 8; ++n2) {
            int colg = q * 128 + n2 * 16 + lhi * 4;
            if (colg >= 704) continue;
            float4 bv = *(const float4*)&bias[colg];
            float v0 = aq[n2][0] + bv.x, v1 = aq[n2][1] + bv.y;
            float v2 = aq[n2][2] + bv.z, v3 = aq[n2][3] + bv.w;
            if (colg < 640) {
                ushort4 o;
                o.x = f2b(v0); o.y = f2b(v1); o.z = f2b(v2); o.w = f2b(v3);
                if (colg < 256)
                    *(ushort4*)&qb[(size_t)rowg * 256 + colg] = o;
                else if (colg < 512)
                    *(ushort4*)&kb[(size_t)rowg * 256 + (colg - 256)] = o;
                else
                    *(ushort4*)&vcb[(size_t)rowg * 128 + (colg - 512)] = o;
            } else {
                float4 o; o.x = v0; o.y = v1; o.z = v2; o.w = v3;
                *(float4*)&outf[(size_t)rowg * 64 + (colg - 640)] = o;
            }
        }
    };

    f32x4 accA[8] = {}, accB[8] = {}, accC[8] = {};
    // ---- PASS A: tiles 0..5 (quads 0,1,2) ----
#pragma unroll
    for (int t = 0; t < 6; ++t) {
        asm volatile("s_waitcnt vmcnt(4)\ns_barrier" ::: "memory");
        __builtin_amdgcn_sched_barrier(0);
        stTile(t + 3);
        const int qi = t >> 1;
        const u16* lBc = lB[t & 3];
#pragma unroll
        for (int ks = 0; ks < 2; ++ks) {
            bf16x8 bf[8];
#pragma unroll
            for (int n2 = 0; n2 < 8; ++n2) {
                int chunk = (ks * 4 + lhi) ^ (lrow & 7);
                bf[n2] = *(const bf16x8*)&lBc[(size_t)(n2 * 16 + lrow) * 64 + chunk * 8];
            }
            if (qi == 0) {
#pragma unroll
                for (int n2 = 0; n2 < 8; ++n2)
                    accA[n2] = __builtin_amdgcn_mfma_f32_16x16x32_bf16(
                        bf[n2], af[(t & 1) * 2 + ks], accA[n2], 0, 0, 0);
            } else if (qi == 1) {
#pragma unroll
                for (int n2 = 0; n2 < 8; ++n2)
                    accB[n2] = __builtin_amdgcn_mfma_f32_16x16x32_bf16(
                        bf[n2], af[(t & 1) * 2 + ks], accB[n2], 0, 0, 0);
            } else {
#pragma unroll
                for (int n2 = 0; n2 < 8; ++n2)
                    accC[n2] = __builtin_amdgcn_mfma_f32_16x16x32_bf16(
                        bf[n2], af[(t & 1) * 2 + ks], accC[n2], 0, 0, 0);
            }
        }
    }
    storeq(0, accA); storeq(1, accB); storeq(2, accC);
#pragma unroll
    for (int n2 = 0; n2 < 8; ++n2) {
        accA[n2] = (f32x4){0.f, 0.f, 0.f, 0.f};
        accB[n2] = (f32x4){0.f, 0.f, 0.f, 0.f};
        accC[n2] = (f32x4){0.f, 0.f, 0.f, 0.f};
    }

    // ---- PASS B: tiles 6..11 (quads 3,4,5) ----
#pragma unroll
    for (int tt = 0; tt < 6; ++tt) {
        if (tt <= 3) {
            asm volatile("s_waitcnt vmcnt(4)\ns_barrier" ::: "memory");
            __builtin_amdgcn_sched_barrier(0);
        } else if (tt == 4) {
            asm volatile("s_waitcnt vmcnt(2)\ns_barrier" ::: "memory");
            __builtin_amdgcn_sched_barrier(0);
        } else {
            asm volatile("s_waitcnt vmcnt(0)\ns_barrier" ::: "memory");
            __builtin_amdgcn_sched_barrier(0);
        }
        if (tt <= 2) stTile(9 + tt);
        const int t = 6 + tt;
        const int qi = tt >> 1;
        const u16* lBc = lB[t & 3];
#pragma unroll
        for (int ks = 0; ks < 2; ++ks) {
            bf16x8 bf[8];
#pragma unroll
            for (int n2 = 0; n2 < 8; ++n2) {
                int chunk = (ks * 4 + lhi) ^ (lrow & 7);
                bf[n2] = *(const bf16x8*)&lBc[(size_t)(n2 * 16 + lrow) * 64 + chunk * 8];
            }
            if (qi == 0) {
#pragma unroll
                for (int n2 = 0; n2 < 8; ++n2)
                    accA[n2] = __builtin_amdgcn_mfma_f32_16x16x32_bf16(
                        bf[n2], af[(tt & 1) * 2 + ks], accA[n2], 0, 0, 0);
            } else if (qi == 1) {
#pragma unroll
                for (int n2 = 0; n2 < 8; ++n2)
                    accB[n2] = __builtin_amdgcn_mfma_f32_16x16x32_bf16(
                        bf[n2], af[(tt & 1) * 2 + ks], accB[n2], 0, 0, 0);
            } else {
#pragma unroll
                for (int n2 = 0; n2 < 8; ++n2)
                    accC[n2] = __builtin_amdgcn_mfma_f32_16x16x32_bf16(
                        bf[n2], af[(tt & 1) * 2 + ks], accC[n2], 0, 0, 0);
            }
        }
    }
    storeq(3, accA); storeq(4, accB); storeq(5, accC);
}

// ---------------- CSR attention: one wave per dst, no atomics ----------------
__global__ __launch_bounds__(256) void k_attn(
    const u16* __restrict__ qB, const u16* __restrict__ kB, const u16* __restrict__ vcB,
    const int* __restrict__ startA, const int* __restrict__ deg,
    const int* __restrict__ esrc, float* __restrict__ out) {
    int wid = threadIdx.x >> 6, lane = threadIdx.x & 63;
    int dst = blockIdx.x * 4 + wid;
    if (dst >= N_NODES) return;
    int d = deg[dst];
    if (d == 0) return;
    int st = startA[dst];

    ushort4 qv = *(const ushort4*)&qB[(size_t)dst * 256 + lane * 4];
    float q0 = b2f(qv.x), q1 = b2f(qv.y), q2 = b2f(qv.z), q3 = b2f(qv.w);
    const float inv = 0.08838834764831845f;  // 1/sqrt(128)

    float s0 = 0.f, s1 = 0.f, accA = 0.f, accB = 0.f;
    int src = esrc[st];
    for (int p = st; p < st + d; ++p) {
        int src_next = (p + 1 < st + d) ? esrc[p + 1] : 0;
        ushort4 kv = *(const ushort4*)&kB[(size_t)src * 256 + lane * 4];
        float v0 = b2f(vcB[(size_t)src * 128 + lane]);
        float v1 = b2f(vcB[(size_t)src * 128 + 64 + lane]);
        float pp = q0 * b2f(kv.x) + q1 * b2f(kv.y) + q2 * b2f(kv.z) + q3 * b2f(kv.w);
        pp += __shfl_xor(pp, 1);
        pp += __shfl_xor(pp, 2);
        pp += __shfl_xor(pp, 4);
        pp += __shfl_xor(pp, 8);
        pp += __shfl_xor(pp, 16);
        float e = __expf(pp * inv);
        float eo = __shfl_xor(e, 32);
        float e0 = (lane < 32) ? e : eo;
        float e1 = (lane < 32) ? eo : e;
        s0 += e0; s1 += e1;
        accA += e0 * v0;
        accB += e1 * v1;
        src = src_next;
    }
    float* op = out + (size_t)dst * 64 + lane;
    *op += accA / s0 + accB / s1;
}

extern "C" void kernel_launch(void* const* d_in, const int* in_sizes, int n_in,
                              void* d_out, int out_size, void* d_ws, size_t ws_size,
                              hipStream_t stream) {
    const float* memory = (const float*)d_in[0];
    const float* W1 = (const float*)d_in[1];  const float* b1 = (const float*)d_in[2];
    const float* W2 = (const float*)d_in[3];  const float* b2 = (const float*)d_in[4];
    const float* Wih = (const float*)d_in[5]; const float* Whh = (const float*)d_in[6];
    const float* bih = (const float*)d_in[7]; const float* bhh = (const float*)d_in[8];
    const float* Wq = (const float*)d_in[9];  const float* bq = (const float*)d_in[10];
    const float* Wk = (const float*)d_in[11]; const float* bk = (const float*)d_in[12];
    const float* Wv = (const float*)d_in[13]; const float* bv = (const float*)d_in[14];
    const float* Ws = (const float*)d_in[15]; const float* bs = (const float*)d_in[16];
    const float* Wc = (const float*)d_in[17]; const float* bc = (const float*)d_in[18];
    const float* eattr = (const float*)d_in[19];
    const int* ei = (const int*)d_in[21];
    float* out = (float*)d_out;

    char* ws = (char*)d_ws;
    size_t off = 0;
    auto alloc = [&](size_t bytes) -> char* {
        char* p = ws + off;
        off = (off + bytes + 255) & ~(size_t)255;
        return p;
    };
    u16* xb = (u16*)alloc((size_t)NPAD * 128 * 2);
    u16* qb = (u16*)alloc((size_t)NPAD * 256 * 2);
    u16* kb = (u16*)alloc((size_t)NPAD * 256 * 2);
    u16* vcb = (u16*)alloc((size_t)NPAD * 128 * 2);
    int* winner = (int*)alloc((size_t)N_NODES * 4);
    int* wnode = (int*)alloc((size_t)N_NODES * 4);
    int* wedge = (int*)alloc((size_t)N_NODES * 4);
    int* wsrc = (int*)alloc((size_t)N_NODES * 4);
    int* deg = (int*)alloc((size_t)N_NODES * 4);
    int* startA = (int*)alloc((size_t)N_NODES * 4);
    int* cursor = (int*)alloc((size_t)N_NODES * 4);
    int* esrc = (int*)alloc((size_t)E_EDGES * 4);
    int* counters = (int*)alloc(256);
    u16* W1p = (u16*)alloc(49152 * 2);
    u16* Wcat2p = (u16*)alloc(131072 * 2);
    u16* Wprojp = (u16*)alloc(98304 * 2);
    float* bias2 = (float*)alloc(512 * 4);
    float* bproj = (float*)alloc(768 * 4);
    (void)ws_size; (void)in_sizes; (void)n_in; (void)out_size;

    int* wcount = counters;  // counters[0]=wcount, counters[1]=etot

    hipLaunchKernelGGL(k_init, dim3(391), dim3(256), 0, stream, winner, deg, counters);
    hipLaunchKernelGGL(k_edges, dim3(1563), dim3(256), 0, stream, ei, winner, deg);
    hipLaunchKernelGGL(k_nodes, dim3(391), dim3(256), 0, stream,
                       winner, deg, ei, wnode, wedge, wsrc, counters, startA, cursor);
    hipLaunchKernelGGL(k_fill, dim3(1563), dim3(256), 0, stream, ei, cursor, esrc);
    hipLaunchKernelGGL(k_pack, dim3(579), dim3(256), 0, stream,
                       W1, Wq, Wk, Wv, Ws, Wc, bq, bk, bv, bs, bc, W1p, Wprojp, bproj);
    hipLaunchKernelGGL(k_fold, dim3(512), dim3(128), 0, stream,
                       W2, Wih, Whh, bih, bhh, b2, Wcat2p, bias2);
    hipLaunchKernelGGL(k_xinit, dim3(12500), dim3(256), 0, stream, memory, winner, xb);
    // fused gather + MLP + GRU for winner rows (512-thread, 2 row-groups)
    hipLaunchKernelGGL(k_mg, dim3(782), dim3(512), 0, stream,
                       memory, eattr, wnode, wedge, wsrc, wcount,
                       W1p, b1, Wcat2p, bias2, xb);
    // proj: [q|k|vc|skip] = xb @ Wproj + bproj  (512-thread, 2 row-groups)
    hipLaunchKernelGGL(k_proj, dim3(782), dim3(512), 0, stream,
                       xb, Wprojp, bproj, N_NODES, qb, kb, vcb, out);
    // CSR attention: out[dst] += sum(alpha * vc[src]) per head, no atomics
    hipLaunchKernelGGL(k_attn, dim3(25000), dim3(256), 0, stream,
                       qb, kb, vcb, startA, deg, esrc, out);
}